// Round 1
// baseline (515.424 us; speedup 1.0000x reference)
//
#include <hip/hip_runtime.h>

// ---------------- problem constants ----------------
#define D_MODEL 1024
#define D_STATE 16
#define D_CONV  4
#define D_INNER 2048
#define DT_RANK 16
#define BATCH   2
#define SEQ     1024
#define M_ROWS  (BATCH*SEQ)   // 2048 rows

typedef __bf16 bf16x8 __attribute__((ext_vector_type(8)));
typedef float  f32x4  __attribute__((ext_vector_type(4)));

__device__ __forceinline__ unsigned short f2bf(float f) {
  unsigned u = __float_as_uint(f);
  u += 0x7fffu + ((u >> 16) & 1u);      // round-to-nearest-even
  return (unsigned short)(u >> 16);
}

__device__ __forceinline__ float sigmoid_fast(float v) {
  return 1.f / (1.f + __expf(-v));
}

// ---------------- cast f32 -> bf16 (x, in_proj_w, out_proj_w fused) ----------------
__global__ __launch_bounds__(256) void cast_all_kernel(
    const float* __restrict__ x, const float* __restrict__ w1, const float* __restrict__ w2,
    unsigned short* __restrict__ xbf, unsigned short* __restrict__ w1bf,
    unsigned short* __restrict__ w2bf) {
  const int N0 = (M_ROWS * D_MODEL) / 4;        // 524288 float4
  const int N1 = (2 * D_INNER * D_MODEL) / 4;   // 1048576 float4
  int i = blockIdx.x * 256 + threadIdx.x;
  const float* src; unsigned short* dst; int off;
  if (i < N0)            { src = x;  dst = xbf;  off = i; }
  else if (i < N0 + N1)  { src = w1; dst = w1bf; off = i - N0; }
  else                   { src = w2; dst = w2bf; off = i - N0 - N1; }
  float4 v = *(const float4*)(src + (size_t)off * 4);
  ushort4 o;
  o.x = f2bf(v.x); o.y = f2bf(v.y); o.z = f2bf(v.z); o.w = f2bf(v.w);
  *(ushort4*)(dst + (size_t)off * 4) = o;
}

// ---------------- bf16 MFMA GEMM, NT: C[M,N] = A[M,K] @ B[N,K]^T + bias[N] ----------------
// 128x128 tile, 4 waves (2x2), each wave 64x64 = 4x4 fragments of 16x16, BK=32.
__global__ __launch_bounds__(256) void gemm_bf16_nt(
    const __bf16* __restrict__ A, const __bf16* __restrict__ B,
    const float* __restrict__ bias, float* __restrict__ C,
    int M, int N, int K) {
  __shared__ __bf16 As[128][40];   // +8 pad: stride 20 words -> 2-way conflict (free)
  __shared__ __bf16 Bs[128][40];
  const int tid  = threadIdx.x;
  const int lane = tid & 63;
  const int w    = tid >> 6;
  const int wr   = w >> 1, wc = w & 1;
  const int rowBase = blockIdx.y * 128;
  const int colBase = blockIdx.x * 128;

  f32x4 acc[4][4];
  #pragma unroll
  for (int i = 0; i < 4; ++i)
    #pragma unroll
    for (int j = 0; j < 4; ++j) {
      f32x4 z = {0.f, 0.f, 0.f, 0.f};
      acc[i][j] = z;
    }

  const int sr = tid >> 2;          // 0..63 staging row
  const int ss = (tid & 3) * 8;     // 0,8,16,24 staging k-offset
  const int fr = lane & 15;
  const int fk = (lane >> 4) * 8;

  for (int k0 = 0; k0 < K; k0 += 32) {
    const __bf16* Ap = A + (size_t)(rowBase + sr) * K + k0 + ss;
    const __bf16* Bp = B + (size_t)(colBase + sr) * K + k0 + ss;
    *(bf16x8*)&As[sr][ss]      = *(const bf16x8*)Ap;
    *(bf16x8*)&As[sr + 64][ss] = *(const bf16x8*)(Ap + (size_t)64 * K);
    *(bf16x8*)&Bs[sr][ss]      = *(const bf16x8*)Bp;
    *(bf16x8*)&Bs[sr + 64][ss] = *(const bf16x8*)(Bp + (size_t)64 * K);
    __syncthreads();

    bf16x8 af[4], bfr[4];
    #pragma unroll
    for (int mm = 0; mm < 4; ++mm)
      af[mm] = *(const bf16x8*)&As[wr * 64 + mm * 16 + fr][fk];
    #pragma unroll
    for (int nn = 0; nn < 4; ++nn)
      bfr[nn] = *(const bf16x8*)&Bs[wc * 64 + nn * 16 + fr][fk];
    #pragma unroll
    for (int mm = 0; mm < 4; ++mm)
      #pragma unroll
      for (int nn = 0; nn < 4; ++nn)
        acc[mm][nn] = __builtin_amdgcn_mfma_f32_16x16x32_bf16(af[mm], bfr[nn], acc[mm][nn], 0, 0, 0);
    __syncthreads();
  }

  // epilogue: C/D layout col=lane&15, row=(lane>>4)*4+reg  [verified m89/m91]
  #pragma unroll
  for (int nn = 0; nn < 4; ++nn) {
    int col = colBase + wc * 64 + nn * 16 + (lane & 15);
    float bv = bias[col];
    #pragma unroll
    for (int mm = 0; mm < 4; ++mm) {
      int row0 = rowBase + wr * 64 + mm * 16 + (lane >> 4) * 4;
      #pragma unroll
      for (int r = 0; r < 4; ++r)
        C[(size_t)(row0 + r) * N + col] = acc[mm][nn][r] + bv;
    }
  }
}

// ---------------- causal depthwise conv (k=4) + bias + SiLU ----------------
// reads xs-branch (cols 0..2047) of x_and_res [2048, 4096]; writes xs f32 [2048, 2048]
__global__ __launch_bounds__(256) void conv_silu_kernel(
    const float* __restrict__ xar, const float* __restrict__ cw,
    const float* __restrict__ cb, float* __restrict__ xs) {
  int idx = blockIdx.x * 256 + threadIdx.x;     // one float4 of d per thread
  int m  = idx >> 9;                            // row (b*1024 + t)
  int d4 = (idx & 511) << 2;                    // d offset
  int t  = m & (SEQ - 1);
  float a0 = 0.f, a1 = 0.f, a2 = 0.f, a3 = 0.f;
  #pragma unroll
  for (int j = 0; j < 4; ++j) {
    int tt = t - 3 + j;
    if (tt < 0) continue;                       // causal left zero-pad (per batch)
    const float4 v = *(const float4*)&xar[(size_t)(m - 3 + j) * (2 * D_INNER) + d4];
    a0 += v.x * cw[(d4 + 0) * 4 + j];
    a1 += v.y * cw[(d4 + 1) * 4 + j];
    a2 += v.z * cw[(d4 + 2) * 4 + j];
    a3 += v.w * cw[(d4 + 3) * 4 + j];
  }
  a0 += cb[d4 + 0]; a1 += cb[d4 + 1]; a2 += cb[d4 + 2]; a3 += cb[d4 + 3];
  float4 o;
  o.x = a0 * sigmoid_fast(a0);
  o.y = a1 * sigmoid_fast(a1);
  o.z = a2 * sigmoid_fast(a2);
  o.w = a3 * sigmoid_fast(a3);
  *(float4*)&xs[(size_t)m * D_INNER + d4] = o;
}

// ---------------- x_proj: [2048,48] = xs[2048,2048] @ xpw[48,2048]^T + b; split dlt/B/C ----------------
__global__ __launch_bounds__(256) void xproj_kernel(
    const float* __restrict__ xs, const float* __restrict__ xpw, const float* __restrict__ xpb,
    float* __restrict__ dlt, float* __restrict__ Bm, float* __restrict__ Cm) {
  __shared__ float xt[16][64];
  __shared__ float wt[48][68];                  // pad 64->68 keeps float4 align, 2-way max
  int tid = threadIdx.x;
  int m0  = blockIdx.x * 16;
  int row = tid >> 4;                           // 0..15
  int c0  = (tid & 15) * 3;                     // 0,3,...,45
  float acc0 = 0.f, acc1 = 0.f, acc2 = 0.f;
  for (int k0 = 0; k0 < D_INNER; k0 += 64) {
    *(float4*)&xt[tid >> 4][(tid & 15) * 4] =
        *(const float4*)&xs[(size_t)(m0 + (tid >> 4)) * D_INNER + k0 + (tid & 15) * 4];
    #pragma unroll
    for (int p = 0; p < 3; ++p) {
      int c = tid + p * 256;                    // 0..767 float4 chunks of 48x64
      int rw = c >> 4, sg = (c & 15) * 4;
      *(float4*)&wt[rw][sg] = *(const float4*)&xpw[(size_t)rw * D_INNER + k0 + sg];
    }
    __syncthreads();
    #pragma unroll 8
    for (int kk = 0; kk < 64; ++kk) {
      float xv = xt[row][kk];
      acc0 += xv * wt[c0 + 0][kk];
      acc1 += xv * wt[c0 + 1][kk];
      acc2 += xv * wt[c0 + 2][kk];
    }
    __syncthreads();
  }
  int m = m0 + row;
  float vals[3] = {acc0 + xpb[c0], acc1 + xpb[c0 + 1], acc2 + xpb[c0 + 2]};
  #pragma unroll
  for (int j = 0; j < 3; ++j) {
    int c = c0 + j;
    float v = vals[j];
    if (c < 16)      dlt[m * 16 + c]        = v;
    else if (c < 32) Bm[m * 16 + (c - 16)]  = v;
    else             Cm[m * 16 + (c - 32)]  = v;
  }
}

// ---------------- fused dt_proj+softplus + selective scan + skip + gate + bf16 cast ----------------
// block = (16 d-channels) x (16 states); grid = (128 d-blocks, 2 batches)
__global__ __launch_bounds__(256) void scan_kernel(
    const float* __restrict__ xs,   // [2048, 2048]
    const float* __restrict__ xar,  // [2048, 4096] (res = cols 2048..4095)
    const float* __restrict__ dlt,  // [2048, 16]
    const float* __restrict__ Bmat, // [2048, 16]
    const float* __restrict__ Cmat, // [2048, 16]
    const float* __restrict__ dtw,  // [2048, 16]
    const float* __restrict__ dtb,  // [2048]
    const float* __restrict__ alog, // [2048, 16]
    const float* __restrict__ Dvec, // [2048]
    unsigned short* __restrict__ ybf) { // [2048, 2048] bf16
  __shared__ float dltc[64][16], Bc[64][16], Cc[64][16];
  __shared__ float xsc[64][16], resc[64][16], deltac[64][16], yc[64][16];
  __shared__ float dtwl[16][17];

  const int tid = threadIdx.x;
  const int b   = blockIdx.y;
  const int d0  = blockIdx.x * 16;
  const int n   = tid & 15;       // state index
  const int dl  = tid >> 4;       // local channel
  const int d   = d0 + dl;

  const float An = -__expf(alog[d * 16 + n]);
  const float Dn = Dvec[d];
  dtwl[dl][n] = dtw[d * 16 + n];

  float h = 0.f;
  for (int t0 = 0; t0 < SEQ; t0 += 64) {
    __syncthreads();   // protect LDS reuse across chunks (and dtwl first use)
    #pragma unroll
    for (int p = 0; p < 4; ++p) {
      int e = tid + p * 256;
      int tt = e >> 4, c = e & 15;
      int rowg = b * SEQ + t0 + tt;
      dltc[tt][c] = dlt[rowg * 16 + c];
      Bc[tt][c]   = Bmat[rowg * 16 + c];
      Cc[tt][c]   = Cmat[rowg * 16 + c];
      xsc[tt][c]  = xs[(size_t)rowg * D_INNER + d0 + c];
      resc[tt][c] = xar[(size_t)rowg * (2 * D_INNER) + D_INNER + d0 + c];
    }
    __syncthreads();
    // delta = softplus(dlt @ dtw^T + dtb) for this chunk's 64x16 block
    #pragma unroll
    for (int p = 0; p < 4; ++p) {
      int e = tid + p * 256;
      int tt = e >> 4, c = e & 15;
      float s = dtb[d0 + c];
      #pragma unroll
      for (int r = 0; r < 16; ++r) s += dltc[tt][r] * dtwl[c][r];
      deltac[tt][c] = (s > 20.f) ? s : log1pf(__expf(s));
    }
    __syncthreads();
    // sequential scan over 64 steps
    for (int tt = 0; tt < 64; ++tt) {
      float dv = deltac[tt][dl];
      float xv = xsc[tt][dl];
      float dA = __expf(dv * An);
      h = dA * h + (dv * xv) * Bc[tt][n];
      float p = h * Cc[tt][n];
      p += __shfl_xor(p, 1);
      p += __shfl_xor(p, 2);
      p += __shfl_xor(p, 4);
      p += __shfl_xor(p, 8);           // masks<16 stay within the 16-lane state group
      if (n == 0) yc[tt][dl] = p + xv * Dn;   // + skip D term
    }
    __syncthreads();
    // gate with silu(res), cast to bf16, write out
    #pragma unroll
    for (int p2 = 0; p2 < 4; ++p2) {
      int e = tid + p2 * 256;
      int tt = e >> 4, c = e & 15;
      int rowg = b * SEQ + t0 + tt;
      float r = resc[tt][c];
      float v = yc[tt][c] * (r * sigmoid_fast(r));
      ybf[(size_t)rowg * D_INNER + d0 + c] = f2bf(v);
    }
  }
}

// ---------------- launcher ----------------
extern "C" void kernel_launch(void* const* d_in, const int* in_sizes, int n_in,
                              void* d_out, int out_size, void* d_ws, size_t ws_size,
                              hipStream_t stream) {
  const float* x    = (const float*)d_in[0];
  const float* ipw  = (const float*)d_in[1];
  const float* ipb  = (const float*)d_in[2];
  const float* cw   = (const float*)d_in[3];
  const float* cb   = (const float*)d_in[4];
  const float* xpw  = (const float*)d_in[5];
  const float* xpb  = (const float*)d_in[6];
  const float* dtw  = (const float*)d_in[7];
  const float* dtb  = (const float*)d_in[8];
  const float* alog = (const float*)d_in[9];
  const float* Dv   = (const float*)d_in[10];
  const float* opw  = (const float*)d_in[11];
  const float* opb  = (const float*)d_in[12];
  float* out = (float*)d_out;

  char* ws = (char*)d_ws;
  size_t off = 0;
  auto alloc = [&](size_t bytes) {
    char* p = ws + off;
    off += (bytes + 255) & ~(size_t)255;
    return p;
  };
  unsigned short* xbf  = (unsigned short*)alloc((size_t)M_ROWS * D_MODEL * 2);       // 4 MB
  unsigned short* w1bf = (unsigned short*)alloc((size_t)2 * D_INNER * D_MODEL * 2);  // 8 MB
  unsigned short* w2bf = (unsigned short*)alloc((size_t)D_MODEL * D_INNER * 2);      // 4 MB
  float* xar = (float*)alloc((size_t)M_ROWS * 2 * D_INNER * 4);                      // 32 MB
  float* xsb = (float*)alloc((size_t)M_ROWS * D_INNER * 4);                          // 16 MB
  float* dlt = (float*)alloc((size_t)M_ROWS * 16 * 4);
  float* Bm  = (float*)alloc((size_t)M_ROWS * 16 * 4);
  float* Cm  = (float*)alloc((size_t)M_ROWS * 16 * 4);
  unsigned short* ybf = (unsigned short*)alloc((size_t)M_ROWS * D_INNER * 2);        // 8 MB
  if (off > ws_size) return;  // workspace too small: fail loudly via wrong output

  // 1. casts (x, in_proj_w, out_proj_w)
  cast_all_kernel<<<8192, 256, 0, stream>>>(x, ipw, opw, xbf, w1bf, w2bf);
  // 2. in_proj: x_and_res[2048,4096] = x @ in_proj_w^T + b
  gemm_bf16_nt<<<dim3(4096 / 128, 2048 / 128), 256, 0, stream>>>(
      (const __bf16*)xbf, (const __bf16*)w1bf, ipb, xar, M_ROWS, 2 * D_INNER, D_MODEL);
  // 3. causal conv + silu -> xs
  conv_silu_kernel<<<4096, 256, 0, stream>>>(xar, cw, cb, xsb);
  // 4. x_proj -> dlt/Bm/Cm
  xproj_kernel<<<M_ROWS / 16, 256, 0, stream>>>(xsb, xpw, xpb, dlt, Bm, Cm);
  // 5. fused dt_proj + softplus + scan + skip + gate -> ybf
  scan_kernel<<<dim3(D_INNER / 16, BATCH), 256, 0, stream>>>(
      xsb, xar, dlt, Bm, Cm, dtw, dtb, alog, Dv, ybf);
  // 6. out_proj: out[2048,1024] = y @ out_proj_w^T + b
  gemm_bf16_nt<<<dim3(1024 / 128, 2048 / 128), 256, 0, stream>>>(
      (const __bf16*)ybf, (const __bf16*)w2bf, opb, out, M_ROWS, D_MODEL, D_INNER);
}

// Round 3
// 330.804 us; speedup vs baseline: 1.5581x; 1.5581x over previous
//
#include <hip/hip_runtime.h>

// ---------------- problem constants ----------------
#define D_MODEL 1024
#define D_STATE 16
#define D_CONV  4
#define D_INNER 2048
#define DT_RANK 16
#define BATCH   2
#define SEQ     1024
#define M_ROWS  (BATCH*SEQ)   // 2048 rows
#define CHUNK   32            // timesteps per scan chunk
#define NCHUNK  (SEQ/CHUNK)   // 32 chunks

typedef __bf16 bf16x8 __attribute__((ext_vector_type(8)));
typedef float  f32x4  __attribute__((ext_vector_type(4)));

__device__ __forceinline__ unsigned short f2bf(float f) {
  unsigned u = __float_as_uint(f);
  u += 0x7fffu + ((u >> 16) & 1u);      // round-to-nearest-even
  return (unsigned short)(u >> 16);
}

__device__ __forceinline__ float sigmoid_fast(float v) {
  return 1.f / (1.f + __expf(-v));
}

__device__ __forceinline__ float softplus_f(float s) {
  return (s > 20.f) ? s : __logf(1.f + __expf(s));
}

// ---------------- cast f32 -> bf16 (x, in_proj_w, out_proj_w fused) ----------------
__global__ __launch_bounds__(256) void cast_all_kernel(
    const float* __restrict__ x, const float* __restrict__ w1, const float* __restrict__ w2,
    unsigned short* __restrict__ xbf, unsigned short* __restrict__ w1bf,
    unsigned short* __restrict__ w2bf) {
  const int N0 = (M_ROWS * D_MODEL) / 4;        // 524288 float4
  const int N1 = (2 * D_INNER * D_MODEL) / 4;   // 1048576 float4
  int i = blockIdx.x * 256 + threadIdx.x;
  const float* src; unsigned short* dst; int off;
  if (i < N0)            { src = x;  dst = xbf;  off = i; }
  else if (i < N0 + N1)  { src = w1; dst = w1bf; off = i - N0; }
  else                   { src = w2; dst = w2bf; off = i - N0 - N1; }
  float4 v = *(const float4*)(src + (size_t)off * 4);
  ushort4 o;
  o.x = f2bf(v.x); o.y = f2bf(v.y); o.z = f2bf(v.z); o.w = f2bf(v.w);
  *(ushort4*)(dst + (size_t)off * 4) = o;
}

// ---------------- bf16 MFMA GEMM, NT: C[M,N] = A[M,K] @ B[N,K]^T + bias[N] ----------------
__global__ __launch_bounds__(256) void gemm_bf16_nt(
    const __bf16* __restrict__ A, const __bf16* __restrict__ B,
    const float* __restrict__ bias, float* __restrict__ C,
    int M, int N, int K) {
  __shared__ __bf16 As[128][40];   // +8 pad: 2-way conflict only (free per m136)
  __shared__ __bf16 Bs[128][40];
  const int tid  = threadIdx.x;
  const int lane = tid & 63;
  const int w    = tid >> 6;
  const int wr   = w >> 1, wc = w & 1;
  const int rowBase = blockIdx.y * 128;
  const int colBase = blockIdx.x * 128;

  f32x4 acc[4][4];
  #pragma unroll
  for (int i = 0; i < 4; ++i)
    #pragma unroll
    for (int j = 0; j < 4; ++j) {
      f32x4 z = {0.f, 0.f, 0.f, 0.f};
      acc[i][j] = z;
    }

  const int sr = tid >> 2;
  const int ss = (tid & 3) * 8;
  const int fr = lane & 15;
  const int fk = (lane >> 4) * 8;

  for (int k0 = 0; k0 < K; k0 += 32) {
    const __bf16* Ap = A + (size_t)(rowBase + sr) * K + k0 + ss;
    const __bf16* Bp = B + (size_t)(colBase + sr) * K + k0 + ss;
    *(bf16x8*)&As[sr][ss]      = *(const bf16x8*)Ap;
    *(bf16x8*)&As[sr + 64][ss] = *(const bf16x8*)(Ap + (size_t)64 * K);
    *(bf16x8*)&Bs[sr][ss]      = *(const bf16x8*)Bp;
    *(bf16x8*)&Bs[sr + 64][ss] = *(const bf16x8*)(Bp + (size_t)64 * K);
    __syncthreads();

    bf16x8 af[4], bfr[4];
    #pragma unroll
    for (int mm = 0; mm < 4; ++mm)
      af[mm] = *(const bf16x8*)&As[wr * 64 + mm * 16 + fr][fk];
    #pragma unroll
    for (int nn = 0; nn < 4; ++nn)
      bfr[nn] = *(const bf16x8*)&Bs[wc * 64 + nn * 16 + fr][fk];
    #pragma unroll
    for (int mm = 0; mm < 4; ++mm)
      #pragma unroll
      for (int nn = 0; nn < 4; ++nn)
        acc[mm][nn] = __builtin_amdgcn_mfma_f32_16x16x32_bf16(af[mm], bfr[nn], acc[mm][nn], 0, 0, 0);
    __syncthreads();
  }

  #pragma unroll
  for (int nn = 0; nn < 4; ++nn) {
    int col = colBase + wc * 64 + nn * 16 + (lane & 15);
    float bv = bias[col];
    #pragma unroll
    for (int mm = 0; mm < 4; ++mm) {
      int row0 = rowBase + wr * 64 + mm * 16 + (lane >> 4) * 4;
      #pragma unroll
      for (int r = 0; r < 4; ++r)
        C[(size_t)(row0 + r) * N + col] = acc[mm][nn][r] + bv;
    }
  }
}

// ---------------- causal depthwise conv (k=4) + bias + SiLU ----------------
__global__ __launch_bounds__(256) void conv_silu_kernel(
    const float* __restrict__ xar, const float* __restrict__ cw,
    const float* __restrict__ cb, float* __restrict__ xs) {
  int idx = blockIdx.x * 256 + threadIdx.x;
  int m  = idx >> 9;
  int d4 = (idx & 511) << 2;
  int t  = m & (SEQ - 1);
  float a0 = 0.f, a1 = 0.f, a2 = 0.f, a3 = 0.f;
  #pragma unroll
  for (int j = 0; j < 4; ++j) {
    int tt = t - 3 + j;
    if (tt < 0) continue;
    const float4 v = *(const float4*)&xar[(size_t)(m - 3 + j) * (2 * D_INNER) + d4];
    a0 += v.x * cw[(d4 + 0) * 4 + j];
    a1 += v.y * cw[(d4 + 1) * 4 + j];
    a2 += v.z * cw[(d4 + 2) * 4 + j];
    a3 += v.w * cw[(d4 + 3) * 4 + j];
  }
  a0 += cb[d4 + 0]; a1 += cb[d4 + 1]; a2 += cb[d4 + 2]; a3 += cb[d4 + 3];
  float4 o;
  o.x = a0 * sigmoid_fast(a0);
  o.y = a1 * sigmoid_fast(a1);
  o.z = a2 * sigmoid_fast(a2);
  o.w = a3 * sigmoid_fast(a3);
  *(float4*)&xs[(size_t)m * D_INNER + d4] = o;
}

// ---------------- x_proj: [2048,48] = xs @ xpw^T + b; split dlt/B/C ----------------
__global__ __launch_bounds__(256) void xproj_kernel(
    const float* __restrict__ xs, const float* __restrict__ xpw, const float* __restrict__ xpb,
    float* __restrict__ dlt, float* __restrict__ Bm, float* __restrict__ Cm) {
  __shared__ float xt[16][64];
  __shared__ float wt[48][68];
  int tid = threadIdx.x;
  int m0  = blockIdx.x * 16;
  int row = tid >> 4;
  int c0  = (tid & 15) * 3;
  float acc0 = 0.f, acc1 = 0.f, acc2 = 0.f;
  for (int k0 = 0; k0 < D_INNER; k0 += 64) {
    *(float4*)&xt[tid >> 4][(tid & 15) * 4] =
        *(const float4*)&xs[(size_t)(m0 + (tid >> 4)) * D_INNER + k0 + (tid & 15) * 4];
    #pragma unroll
    for (int p = 0; p < 3; ++p) {
      int c = tid + p * 256;
      int rw = c >> 4, sg = (c & 15) * 4;
      *(float4*)&wt[rw][sg] = *(const float4*)&xpw[(size_t)rw * D_INNER + k0 + sg];
    }
    __syncthreads();
    #pragma unroll 8
    for (int kk = 0; kk < 64; ++kk) {
      float xv = xt[row][kk];
      acc0 += xv * wt[c0 + 0][kk];
      acc1 += xv * wt[c0 + 1][kk];
      acc2 += xv * wt[c0 + 2][kk];
    }
    __syncthreads();
  }
  int m = m0 + row;
  float vals[3] = {acc0 + xpb[c0], acc1 + xpb[c0 + 1], acc2 + xpb[c0 + 2]};
  #pragma unroll
  for (int j = 0; j < 3; ++j) {
    int c = c0 + j;
    float v = vals[j];
    if (c < 16)      dlt[m * 16 + c]        = v;
    else if (c < 32) Bm[m * 16 + (c - 16)]  = v;
    else             Cm[m * 16 + (c - 32)]  = v;
  }
}

// ======================= chunked parallel selective scan =======================
// h_t = exp(dv_t*A)*h_{t-1} + (dv_t*x_t)*B_t ; prefix decay = exp(A * cumsum(dv)).
// Phase1: per-chunk local scan from h=0 -> Hbuf[b][c][d][16] = local h_end, Sbuf = sum(dv).
// Phase2: sequential combine over 32 chunks; Hbuf[b][c][d][n] becomes the TRUE h at
//         chunk START (in-place: read h_end, write h_start).
// Phase3: replay each chunk from true h_start; fuse y, D-skip, gate, bf16 cast.

#define DELTA16(sarr, ttq)                                                       \
  {                                                                              \
    float4 q0 = *(const float4*)&sarr[ttq][0];                                   \
    float4 q1 = *(const float4*)&sarr[ttq][4];                                   \
    float4 q2 = *(const float4*)&sarr[ttq][8];                                   \
    float4 q3 = *(const float4*)&sarr[ttq][12];                                  \
    s += q0.x*dtwr[0] + q0.y*dtwr[1] + q0.z*dtwr[2] + q0.w*dtwr[3];              \
    s += q1.x*dtwr[4] + q1.y*dtwr[5] + q1.z*dtwr[6] + q1.w*dtwr[7];              \
    s += q2.x*dtwr[8] + q2.y*dtwr[9] + q2.z*dtwr[10] + q2.w*dtwr[11];            \
    s += q3.x*dtwr[12] + q3.y*dtwr[13] + q3.z*dtwr[14] + q3.w*dtwr[15];          \
  }

__global__ __launch_bounds__(256) void scan_phase1(
    const float* __restrict__ xs, const float* __restrict__ dlt,
    const float* __restrict__ Bmat, const float* __restrict__ dtw,
    const float* __restrict__ dtb, const float* __restrict__ alog,
    float* __restrict__ Hbuf, float* __restrict__ Sbuf) {
  __shared__ float dltS[CHUNK][16];
  __shared__ float BS[CHUNK][16];
  const int tid = threadIdx.x;
  const int c   = blockIdx.y;
  const int b   = blockIdx.z;
  const int d   = blockIdx.x * 256 + tid;
  const int row0 = b * SEQ + c * CHUNK;
  {
    int e = tid * 2;
    int tt = e >> 4, r = e & 15;
    *(float2*)&dltS[tt][r] = *(const float2*)&dlt[(row0 + tt) * 16 + r];
    *(float2*)&BS[tt][r]   = *(const float2*)&Bmat[(row0 + tt) * 16 + r];
  }
  float dtwr[16], An[16];
  #pragma unroll
  for (int q = 0; q < 4; ++q) {
    float4 w4 = *(const float4*)&dtw[d * 16 + q * 4];
    dtwr[q*4+0] = w4.x; dtwr[q*4+1] = w4.y; dtwr[q*4+2] = w4.z; dtwr[q*4+3] = w4.w;
    float4 a4 = *(const float4*)&alog[d * 16 + q * 4];
    An[q*4+0] = -__expf(a4.x); An[q*4+1] = -__expf(a4.y);
    An[q*4+2] = -__expf(a4.z); An[q*4+3] = -__expf(a4.w);
  }
  const float dtbv = dtb[d];
  float xv[CHUNK];
  #pragma unroll
  for (int tt = 0; tt < CHUNK; ++tt)
    xv[tt] = xs[(size_t)(row0 + tt) * D_INNER + d];
  __syncthreads();
  float dv[CHUNK];
  #pragma unroll
  for (int tt = 0; tt < CHUNK; ++tt) {
    float s = dtbv;
    DELTA16(dltS, tt);
    dv[tt] = softplus_f(s);
  }
  float h[16];
  #pragma unroll
  for (int n = 0; n < 16; ++n) h[n] = 0.f;
  float Ssum = 0.f;
  #pragma unroll
  for (int tt = 0; tt < CHUNK; ++tt) {
    const float dvt = dv[tt];
    Ssum += dvt;
    const float dvx = dvt * xv[tt];
    float4 B0 = *(const float4*)&BS[tt][0];
    float4 B1 = *(const float4*)&BS[tt][4];
    float4 B2 = *(const float4*)&BS[tt][8];
    float4 B3 = *(const float4*)&BS[tt][12];
    h[0]  = __expf(dvt*An[0])*h[0]   + dvx*B0.x;
    h[1]  = __expf(dvt*An[1])*h[1]   + dvx*B0.y;
    h[2]  = __expf(dvt*An[2])*h[2]   + dvx*B0.z;
    h[3]  = __expf(dvt*An[3])*h[3]   + dvx*B0.w;
    h[4]  = __expf(dvt*An[4])*h[4]   + dvx*B1.x;
    h[5]  = __expf(dvt*An[5])*h[5]   + dvx*B1.y;
    h[6]  = __expf(dvt*An[6])*h[6]   + dvx*B1.z;
    h[7]  = __expf(dvt*An[7])*h[7]   + dvx*B1.w;
    h[8]  = __expf(dvt*An[8])*h[8]   + dvx*B2.x;
    h[9]  = __expf(dvt*An[9])*h[9]   + dvx*B2.y;
    h[10] = __expf(dvt*An[10])*h[10] + dvx*B2.z;
    h[11] = __expf(dvt*An[11])*h[11] + dvx*B2.w;
    h[12] = __expf(dvt*An[12])*h[12] + dvx*B3.x;
    h[13] = __expf(dvt*An[13])*h[13] + dvx*B3.y;
    h[14] = __expf(dvt*An[14])*h[14] + dvx*B3.z;
    h[15] = __expf(dvt*An[15])*h[15] + dvx*B3.w;
  }
  size_t hbase = (((size_t)(b * NCHUNK + c) * D_INNER) + d) * 16;
  #pragma unroll
  for (int q = 0; q < 4; ++q) {
    float4 o = {h[q*4+0], h[q*4+1], h[q*4+2], h[q*4+3]};
    *(float4*)&Hbuf[hbase + q*4] = o;
  }
  Sbuf[((size_t)b * NCHUNK + c) * D_INNER + d] = Ssum;
}

__global__ __launch_bounds__(256) void scan_phase2(
    const float* __restrict__ alog, const float* __restrict__ Sbuf,
    float* __restrict__ Hbuf) {
  const int tid = threadIdx.x;
  const int n  = tid & 15;
  const int dl = tid >> 4;
  const int d  = blockIdx.x * 16 + dl;
  const int b  = blockIdx.y;
  const float An = -__expf(alog[d * 16 + n]);
  float h_run = 0.f;
  #pragma unroll 4
  for (int c = 0; c < NCHUNK; ++c) {
    size_t idx = (((size_t)(b * NCHUNK + c) * D_INNER) + d) * 16 + n;
    float hend = Hbuf[idx];
    float P = __expf(An * Sbuf[((size_t)b * NCHUNK + c) * D_INNER + d]);
    Hbuf[idx] = h_run;                     // h at chunk START
    h_run = P * h_run + hend;
  }
}

__global__ __launch_bounds__(256) void scan_phase3(
    const float* __restrict__ xs, const float* __restrict__ xar,
    const float* __restrict__ dlt, const float* __restrict__ Bmat,
    const float* __restrict__ Cmat, const float* __restrict__ dtw,
    const float* __restrict__ dtb, const float* __restrict__ alog,
    const float* __restrict__ Dvec, const float* __restrict__ Hbuf,
    unsigned short* __restrict__ ybf) {
  __shared__ float dltS[CHUNK][16];
  __shared__ float BS[CHUNK][16];
  __shared__ float CS[CHUNK][16];
  const int tid = threadIdx.x;
  const int c   = blockIdx.y;
  const int b   = blockIdx.z;
  const int d   = blockIdx.x * 256 + tid;
  const int row0 = b * SEQ + c * CHUNK;
  {
    int e = tid * 2;
    int tt = e >> 4, r = e & 15;
    *(float2*)&dltS[tt][r] = *(const float2*)&dlt[(row0 + tt) * 16 + r];
    *(float2*)&BS[tt][r]   = *(const float2*)&Bmat[(row0 + tt) * 16 + r];
    *(float2*)&CS[tt][r]   = *(const float2*)&Cmat[(row0 + tt) * 16 + r];
  }
  float dtwr[16], An[16];
  #pragma unroll
  for (int q = 0; q < 4; ++q) {
    float4 w4 = *(const float4*)&dtw[d * 16 + q * 4];
    dtwr[q*4+0] = w4.x; dtwr[q*4+1] = w4.y; dtwr[q*4+2] = w4.z; dtwr[q*4+3] = w4.w;
    float4 a4 = *(const float4*)&alog[d * 16 + q * 4];
    An[q*4+0] = -__expf(a4.x); An[q*4+1] = -__expf(a4.y);
    An[q*4+2] = -__expf(a4.z); An[q*4+3] = -__expf(a4.w);
  }
  const float dtbv = dtb[d];
  const float Dn   = Dvec[d];
  float h[16];
  {
    size_t hbase = (((size_t)(b * NCHUNK + c) * D_INNER) + d) * 16;
    #pragma unroll
    for (int q = 0; q < 4; ++q) {
      float4 hv = *(const float4*)&Hbuf[hbase + q*4];
      h[q*4+0] = hv.x; h[q*4+1] = hv.y; h[q*4+2] = hv.z; h[q*4+3] = hv.w;
    }
  }
  float xv[CHUNK], rv[CHUNK];
  #pragma unroll
  for (int tt = 0; tt < CHUNK; ++tt) {
    xv[tt] = xs[(size_t)(row0 + tt) * D_INNER + d];
    rv[tt] = xar[(size_t)(row0 + tt) * (2 * D_INNER) + D_INNER + d];
  }
  __syncthreads();
  float dv[CHUNK];
  #pragma unroll
  for (int tt = 0; tt < CHUNK; ++tt) {
    float s = dtbv;
    DELTA16(dltS, tt);
    dv[tt] = softplus_f(s);
  }
  #pragma unroll
  for (int tt = 0; tt < CHUNK; ++tt) {
    const float dvt = dv[tt];
    const float dvx = dvt * xv[tt];
    float4 B0 = *(const float4*)&BS[tt][0];
    float4 B1 = *(const float4*)&BS[tt][4];
    float4 B2 = *(const float4*)&BS[tt][8];
    float4 B3 = *(const float4*)&BS[tt][12];
    float4 C0 = *(const float4*)&CS[tt][0];
    float4 C1 = *(const float4*)&CS[tt][4];
    float4 C2 = *(const float4*)&CS[tt][8];
    float4 C3 = *(const float4*)&CS[tt][12];
    float y = 0.f;
    h[0]  = __expf(dvt*An[0])*h[0]   + dvx*B0.x;  y += h[0]*C0.x;
    h[1]  = __expf(dvt*An[1])*h[1]   + dvx*B0.y;  y += h[1]*C0.y;
    h[2]  = __expf(dvt*An[2])*h[2]   + dvx*B0.z;  y += h[2]*C0.z;
    h[3]  = __expf(dvt*An[3])*h[3]   + dvx*B0.w;  y += h[3]*C0.w;
    h[4]  = __expf(dvt*An[4])*h[4]   + dvx*B1.x;  y += h[4]*C1.x;
    h[5]  = __expf(dvt*An[5])*h[5]   + dvx*B1.y;  y += h[5]*C1.y;
    h[6]  = __expf(dvt*An[6])*h[6]   + dvx*B1.z;  y += h[6]*C1.z;
    h[7]  = __expf(dvt*An[7])*h[7]   + dvx*B1.w;  y += h[7]*C1.w;
    h[8]  = __expf(dvt*An[8])*h[8]   + dvx*B2.x;  y += h[8]*C2.x;
    h[9]  = __expf(dvt*An[9])*h[9]   + dvx*B2.y;  y += h[9]*C2.y;
    h[10] = __expf(dvt*An[10])*h[10] + dvx*B2.z;  y += h[10]*C2.z;
    h[11] = __expf(dvt*An[11])*h[11] + dvx*B2.w;  y += h[11]*C2.w;
    h[12] = __expf(dvt*An[12])*h[12] + dvx*B3.x;  y += h[12]*C3.x;
    h[13] = __expf(dvt*An[13])*h[13] + dvx*B3.y;  y += h[13]*C3.y;
    h[14] = __expf(dvt*An[14])*h[14] + dvx*B3.z;  y += h[14]*C3.z;
    h[15] = __expf(dvt*An[15])*h[15] + dvx*B3.w;  y += h[15]*C3.w;
    y += xv[tt] * Dn;
    const float r = rv[tt];
    const float v = y * (r * sigmoid_fast(r));
    ybf[(size_t)(row0 + tt) * D_INNER + d] = f2bf(v);
  }
}

// ---------------- launcher ----------------
extern "C" void kernel_launch(void* const* d_in, const int* in_sizes, int n_in,
                              void* d_out, int out_size, void* d_ws, size_t ws_size,
                              hipStream_t stream) {
  const float* x    = (const float*)d_in[0];
  const float* ipw  = (const float*)d_in[1];
  const float* ipb  = (const float*)d_in[2];
  const float* cw   = (const float*)d_in[3];
  const float* cb   = (const float*)d_in[4];
  const float* xpw  = (const float*)d_in[5];
  const float* xpb  = (const float*)d_in[6];
  const float* dtw  = (const float*)d_in[7];
  const float* dtb  = (const float*)d_in[8];
  const float* alog = (const float*)d_in[9];
  const float* Dv   = (const float*)d_in[10];
  const float* opw  = (const float*)d_in[11];
  const float* opb  = (const float*)d_in[12];
  float* out = (float*)d_out;

  char* ws = (char*)d_ws;
  size_t off = 0;
  auto alloc = [&](size_t bytes) {
    char* p = ws + off;
    off += (bytes + 255) & ~(size_t)255;
    return p;
  };
  unsigned short* xbf  = (unsigned short*)alloc((size_t)M_ROWS * D_MODEL * 2);       // 4 MB
  unsigned short* w1bf = (unsigned short*)alloc((size_t)2 * D_INNER * D_MODEL * 2);  // 8 MB
  unsigned short* w2bf = (unsigned short*)alloc((size_t)D_MODEL * D_INNER * 2);      // 4 MB
  float* xar = (float*)alloc((size_t)M_ROWS * 2 * D_INNER * 4);                      // 32 MB
  float* xsb = (float*)alloc((size_t)M_ROWS * D_INNER * 4);                          // 16 MB
  float* dlt = (float*)alloc((size_t)M_ROWS * 16 * 4);
  float* Bm  = (float*)alloc((size_t)M_ROWS * 16 * 4);
  float* Cm  = (float*)alloc((size_t)M_ROWS * 16 * 4);
  unsigned short* ybf = (unsigned short*)alloc((size_t)M_ROWS * D_INNER * 2);        // 8 MB
  if (off > ws_size) return;
  // scan scratch ALIASES cast buffers (dead after gemm1; stream-ordered, safe):
  //   Hbuf = w1bf region (needs 8 MB == w1bf size), Sbuf = xbf region (0.5 of 4 MB)
  float* Hbuf = (float*)w1bf;   // [B][NCHUNK][D_INNER][16] = 8 MB
  float* Sbuf = (float*)xbf;    // [B][NCHUNK][D_INNER]     = 512 KB

  // 1. casts
  cast_all_kernel<<<8192, 256, 0, stream>>>(x, ipw, opw, xbf, w1bf, w2bf);
  // 2. in_proj
  gemm_bf16_nt<<<dim3(4096 / 128, 2048 / 128), 256, 0, stream>>>(
      (const __bf16*)xbf, (const __bf16*)w1bf, ipb, xar, M_ROWS, 2 * D_INNER, D_MODEL);
  // 3. conv + silu
  conv_silu_kernel<<<4096, 256, 0, stream>>>(xar, cw, cb, xsb);
  // 4. x_proj
  xproj_kernel<<<M_ROWS / 16, 256, 0, stream>>>(xsb, xpw, xpb, dlt, Bm, Cm);
  // 5. chunked scan (3 phases)
  scan_phase1<<<dim3(D_INNER / 256, NCHUNK, BATCH), 256, 0, stream>>>(
      xsb, dlt, Bm, dtw, dtb, alog, Hbuf, Sbuf);
  scan_phase2<<<dim3(D_INNER / 16, BATCH), 256, 0, stream>>>(alog, Sbuf, Hbuf);
  scan_phase3<<<dim3(D_INNER / 256, NCHUNK, BATCH), 256, 0, stream>>>(
      xsb, xar, dlt, Bm, Cm, dtw, dtb, alog, Dv, Hbuf, ybf);
  // 6. out_proj
  gemm_bf16_nt<<<dim3(1024 / 128, 2048 / 128), 256, 0, stream>>>(
      (const __bf16*)ybf, (const __bf16*)w2bf, opb, out, M_ROWS, D_MODEL, D_INNER);
}

// Round 5
// 306.698 us; speedup vs baseline: 1.6806x; 1.0786x over previous
//
#include <hip/hip_runtime.h>

// ---------------- problem constants ----------------
#define D_MODEL 1024
#define D_STATE 16
#define D_CONV  4
#define D_INNER 2048
#define DT_RANK 16
#define BATCH   2
#define SEQ     1024
#define M_ROWS  (BATCH*SEQ)   // 2048 rows
#define CHUNK   32            // timesteps per scan chunk
#define NCHUNK  (SEQ/CHUNK)   // 32 chunks

typedef __bf16 bf16x8 __attribute__((ext_vector_type(8)));
typedef float  f32x4  __attribute__((ext_vector_type(4)));

__device__ __forceinline__ unsigned short f2bf(float f) {
  unsigned u = __float_as_uint(f);
  u += 0x7fffu + ((u >> 16) & 1u);      // round-to-nearest-even
  return (unsigned short)(u >> 16);
}

__device__ __forceinline__ float sigmoid_fast(float v) {
  return 1.f / (1.f + __expf(-v));
}

__device__ __forceinline__ float softplus_f(float s) {
  return (s > 20.f) ? s : __logf(1.f + __expf(s));
}

// ---------------- cast f32 -> bf16 (x, in_proj_w, out_proj_w, x_proj_w) ----------------
__global__ __launch_bounds__(256) void cast_all_kernel(
    const float* __restrict__ x, const float* __restrict__ w1, const float* __restrict__ w2,
    const float* __restrict__ xpw,
    unsigned short* __restrict__ xbf, unsigned short* __restrict__ w1bf,
    unsigned short* __restrict__ w2bf, unsigned short* __restrict__ xpwbf) {
  const int N0 = (M_ROWS * D_MODEL) / 4;        // 524288 float4
  const int N1 = (2 * D_INNER * D_MODEL) / 4;   // 1048576
  const int N2 = (D_MODEL * D_INNER) / 4;       // 524288
  int i = blockIdx.x * 256 + threadIdx.x;       // grid covers N0+N1+N2+N3 exactly
  const float* src; unsigned short* dst; int off;
  if (i < N0)                 { src = x;   dst = xbf;   off = i; }
  else if (i < N0 + N1)       { src = w1;  dst = w1bf;  off = i - N0; }
  else if (i < N0 + N1 + N2)  { src = w2;  dst = w2bf;  off = i - N0 - N1; }
  else                        { src = xpw; dst = xpwbf; off = i - N0 - N1 - N2; }
  float4 v = *(const float4*)(src + (size_t)off * 4);
  ushort4 o;
  o.x = f2bf(v.x); o.y = f2bf(v.y); o.z = f2bf(v.z); o.w = f2bf(v.w);
  *(ushort4*)(dst + (size_t)off * 4) = o;
}

// ---------------- bf16 MFMA GEMM, NT: C[M,N] = A[M,K] @ B[N,K]^T + bias[N] ----------------
__global__ __launch_bounds__(256) void gemm_bf16_nt(
    const __bf16* __restrict__ A, const __bf16* __restrict__ B,
    const float* __restrict__ bias, float* __restrict__ C,
    int M, int N, int K) {
  __shared__ __bf16 As[128][40];   // +8 pad: 2-way conflict only (free per m136)
  __shared__ __bf16 Bs[128][40];
  const int tid  = threadIdx.x;
  const int lane = tid & 63;
  const int w    = tid >> 6;
  const int wr   = w >> 1, wc = w & 1;
  const int rowBase = blockIdx.y * 128;
  const int colBase = blockIdx.x * 128;

  f32x4 acc[4][4];
  #pragma unroll
  for (int i = 0; i < 4; ++i)
    #pragma unroll
    for (int j = 0; j < 4; ++j) {
      f32x4 z = {0.f, 0.f, 0.f, 0.f};
      acc[i][j] = z;
    }

  const int sr = tid >> 2;
  const int ss = (tid & 3) * 8;
  const int fr = lane & 15;
  const int fk = (lane >> 4) * 8;

  for (int k0 = 0; k0 < K; k0 += 32) {
    const __bf16* Ap = A + (size_t)(rowBase + sr) * K + k0 + ss;
    const __bf16* Bp = B + (size_t)(colBase + sr) * K + k0 + ss;
    *(bf16x8*)&As[sr][ss]      = *(const bf16x8*)Ap;
    *(bf16x8*)&As[sr + 64][ss] = *(const bf16x8*)(Ap + (size_t)64 * K);
    *(bf16x8*)&Bs[sr][ss]      = *(const bf16x8*)Bp;
    *(bf16x8*)&Bs[sr + 64][ss] = *(const bf16x8*)(Bp + (size_t)64 * K);
    __syncthreads();

    bf16x8 af[4], bfr[4];
    #pragma unroll
    for (int mm = 0; mm < 4; ++mm)
      af[mm] = *(const bf16x8*)&As[wr * 64 + mm * 16 + fr][fk];
    #pragma unroll
    for (int nn = 0; nn < 4; ++nn)
      bfr[nn] = *(const bf16x8*)&Bs[wc * 64 + nn * 16 + fr][fk];
    #pragma unroll
    for (int mm = 0; mm < 4; ++mm)
      #pragma unroll
      for (int nn = 0; nn < 4; ++nn)
        acc[mm][nn] = __builtin_amdgcn_mfma_f32_16x16x32_bf16(af[mm], bfr[nn], acc[mm][nn], 0, 0, 0);
    __syncthreads();
  }

  #pragma unroll
  for (int nn = 0; nn < 4; ++nn) {
    int col = colBase + wc * 64 + nn * 16 + (lane & 15);
    float bv = bias[col];
    #pragma unroll
    for (int mm = 0; mm < 4; ++mm) {
      int row0 = rowBase + wr * 64 + mm * 16 + (lane >> 4) * 4;
      #pragma unroll
      for (int r = 0; r < 4; ++r)
        C[(size_t)(row0 + r) * N + col] = acc[mm][nn][r] + bv;
    }
  }
}

// ---------------- causal depthwise conv (k=4) + bias + SiLU (emit f32 + bf16) ----------------
__global__ __launch_bounds__(256) void conv_silu_kernel(
    const float* __restrict__ xar, const float* __restrict__ cw,
    const float* __restrict__ cb, float* __restrict__ xs,
    unsigned short* __restrict__ xsbf) {
  int idx = blockIdx.x * 256 + threadIdx.x;
  int m  = idx >> 9;
  int d4 = (idx & 511) << 2;
  int t  = m & (SEQ - 1);
  float a0 = 0.f, a1 = 0.f, a2 = 0.f, a3 = 0.f;
  #pragma unroll
  for (int j = 0; j < 4; ++j) {
    int tt = t - 3 + j;
    if (tt < 0) continue;
    const float4 v = *(const float4*)&xar[(size_t)(m - 3 + j) * (2 * D_INNER) + d4];
    a0 += v.x * cw[(d4 + 0) * 4 + j];
    a1 += v.y * cw[(d4 + 1) * 4 + j];
    a2 += v.z * cw[(d4 + 2) * 4 + j];
    a3 += v.w * cw[(d4 + 3) * 4 + j];
  }
  a0 += cb[d4 + 0]; a1 += cb[d4 + 1]; a2 += cb[d4 + 2]; a3 += cb[d4 + 3];
  float4 o;
  o.x = a0 * sigmoid_fast(a0);
  o.y = a1 * sigmoid_fast(a1);
  o.z = a2 * sigmoid_fast(a2);
  o.w = a3 * sigmoid_fast(a3);
  *(float4*)&xs[(size_t)m * D_INNER + d4] = o;
  ushort4 ob;
  ob.x = f2bf(o.x); ob.y = f2bf(o.y); ob.z = f2bf(o.z); ob.w = f2bf(o.w);
  *(ushort4*)&xsbf[(size_t)m * D_INNER + d4] = ob;
}

// ---------------- x_proj via MFMA: [2048,48] = xs_bf @ xpw_bf^T + b; split dlt/B/C ----------------
// 128-row tile, 4 waves (each 32 rows = 2 M-frags x 3 N-frags), BK=32, grid=16.
__global__ __launch_bounds__(256) void xproj_mfma(
    const __bf16* __restrict__ A, const __bf16* __restrict__ B,
    const float* __restrict__ xpb,
    float* __restrict__ dlt, float* __restrict__ Bm, float* __restrict__ Cm) {
  __shared__ __bf16 As[128][40];
  __shared__ __bf16 Bs[48][40];
  const int tid  = threadIdx.x;
  const int lane = tid & 63;
  const int w    = tid >> 6;                    // wave: rows w*32 .. w*32+31
  const int rowBase = blockIdx.x * 128;

  f32x4 acc[2][3];
  #pragma unroll
  for (int i = 0; i < 2; ++i)
    #pragma unroll
    for (int j = 0; j < 3; ++j) {
      f32x4 z = {0.f, 0.f, 0.f, 0.f};
      acc[i][j] = z;
    }

  const int sr = tid >> 2;          // 0..63
  const int ss = (tid & 3) * 8;     // 0,8,16,24
  const int fr = lane & 15;
  const int fk = (lane >> 4) * 8;

  for (int k0 = 0; k0 < D_INNER; k0 += 32) {
    const __bf16* Ap = A + (size_t)(rowBase + sr) * D_INNER + k0 + ss;
    *(bf16x8*)&As[sr][ss]      = *(const bf16x8*)Ap;
    *(bf16x8*)&As[sr + 64][ss] = *(const bf16x8*)(Ap + (size_t)64 * D_INNER);
    if (tid < 192)
      *(bf16x8*)&Bs[tid >> 2][ss] = *(const bf16x8*)(B + (size_t)(tid >> 2) * D_INNER + k0 + ss);
    __syncthreads();

    bf16x8 af[2], bfr[3];
    #pragma unroll
    for (int mm = 0; mm < 2; ++mm)
      af[mm] = *(const bf16x8*)&As[w * 32 + mm * 16 + fr][fk];
    #pragma unroll
    for (int nn = 0; nn < 3; ++nn)
      bfr[nn] = *(const bf16x8*)&Bs[nn * 16 + fr][fk];
    #pragma unroll
    for (int mm = 0; mm < 2; ++mm)
      #pragma unroll
      for (int nn = 0; nn < 3; ++nn)
        acc[mm][nn] = __builtin_amdgcn_mfma_f32_16x16x32_bf16(af[mm], bfr[nn], acc[mm][nn], 0, 0, 0);
    __syncthreads();
  }

  // C/D layout: col = lane&15, row = (lane>>4)*4 + reg
  const int c16 = lane & 15;
  #pragma unroll
  for (int nn = 0; nn < 3; ++nn) {
    float bv = xpb[nn * 16 + c16];
    float* dst = (nn == 0) ? dlt : (nn == 1) ? Bm : Cm;
    #pragma unroll
    for (int mm = 0; mm < 2; ++mm) {
      int row0 = rowBase + w * 32 + mm * 16 + (lane >> 4) * 4;
      #pragma unroll
      for (int r = 0; r < 4; ++r)
        dst[(size_t)(row0 + r) * 16 + c16] = acc[mm][nn][r] + bv;
    }
  }
}

// ======================= chunked parallel selective scan =======================
// h_t = exp(dv_t*A)*h_{t-1} + (dv_t*x_t)*B_t ; prefix decay = exp(A * cumsum(dv)).
// Phase1: per-chunk local scan from h=0 -> Hbuf[b][c][d][16] = local h_end, Sbuf = sum(dv).
// Phase2: sequential combine over 32 chunks; Hbuf becomes TRUE h at chunk START (in-place).
// Phase3: replay each chunk from true h_start; fuse y, D-skip, gate, bf16 cast.

#define DELTA16(sarr, ttq)                                                       \
  {                                                                              \
    float4 q0 = *(const float4*)&sarr[ttq][0];                                   \
    float4 q1 = *(const float4*)&sarr[ttq][4];                                   \
    float4 q2 = *(const float4*)&sarr[ttq][8];                                   \
    float4 q3 = *(const float4*)&sarr[ttq][12];                                  \
    s += q0.x*dtwr[0] + q0.y*dtwr[1] + q0.z*dtwr[2] + q0.w*dtwr[3];              \
    s += q1.x*dtwr[4] + q1.y*dtwr[5] + q1.z*dtwr[6] + q1.w*dtwr[7];              \
    s += q2.x*dtwr[8] + q2.y*dtwr[9] + q2.z*dtwr[10] + q2.w*dtwr[11];            \
    s += q3.x*dtwr[12] + q3.y*dtwr[13] + q3.z*dtwr[14] + q3.w*dtwr[15];          \
  }

__global__ __launch_bounds__(256) void scan_phase1(
    const float* __restrict__ xs, const float* __restrict__ dlt,
    const float* __restrict__ Bmat, const float* __restrict__ dtw,
    const float* __restrict__ dtb, const float* __restrict__ alog,
    float* __restrict__ Hbuf, float* __restrict__ Sbuf) {
  __shared__ float dltS[CHUNK][16];
  __shared__ float BS[CHUNK][16];
  const int tid = threadIdx.x;
  const int c   = blockIdx.y;
  const int b   = blockIdx.z;
  const int d   = blockIdx.x * 256 + tid;
  const int row0 = b * SEQ + c * CHUNK;
  {
    int e = tid * 2;
    int tt = e >> 4, r = e & 15;
    *(float2*)&dltS[tt][r] = *(const float2*)&dlt[(row0 + tt) * 16 + r];
    *(float2*)&BS[tt][r]   = *(const float2*)&Bmat[(row0 + tt) * 16 + r];
  }
  float dtwr[16], An[16];
  #pragma unroll
  for (int q = 0; q < 4; ++q) {
    float4 w4 = *(const float4*)&dtw[d * 16 + q * 4];
    dtwr[q*4+0] = w4.x; dtwr[q*4+1] = w4.y; dtwr[q*4+2] = w4.z; dtwr[q*4+3] = w4.w;
    float4 a4 = *(const float4*)&alog[d * 16 + q * 4];
    An[q*4+0] = -__expf(a4.x); An[q*4+1] = -__expf(a4.y);
    An[q*4+2] = -__expf(a4.z); An[q*4+3] = -__expf(a4.w);
  }
  const float dtbv = dtb[d];
  float xv[CHUNK];
  #pragma unroll
  for (int tt = 0; tt < CHUNK; ++tt)
    xv[tt] = xs[(size_t)(row0 + tt) * D_INNER + d];
  __syncthreads();
  float dv[CHUNK];
  #pragma unroll
  for (int tt = 0; tt < CHUNK; ++tt) {
    float s = dtbv;
    DELTA16(dltS, tt);
    dv[tt] = softplus_f(s);
  }
  float h[16];
  #pragma unroll
  for (int n = 0; n < 16; ++n) h[n] = 0.f;
  float Ssum = 0.f;
  #pragma unroll
  for (int tt = 0; tt < CHUNK; ++tt) {
    const float dvt = dv[tt];
    Ssum += dvt;
    const float dvx = dvt * xv[tt];
    float4 B0 = *(const float4*)&BS[tt][0];
    float4 B1 = *(const float4*)&BS[tt][4];
    float4 B2 = *(const float4*)&BS[tt][8];
    float4 B3 = *(const float4*)&BS[tt][12];
    h[0]  = __expf(dvt*An[0])*h[0]   + dvx*B0.x;
    h[1]  = __expf(dvt*An[1])*h[1]   + dvx*B0.y;
    h[2]  = __expf(dvt*An[2])*h[2]   + dvx*B0.z;
    h[3]  = __expf(dvt*An[3])*h[3]   + dvx*B0.w;
    h[4]  = __expf(dvt*An[4])*h[4]   + dvx*B1.x;
    h[5]  = __expf(dvt*An[5])*h[5]   + dvx*B1.y;
    h[6]  = __expf(dvt*An[6])*h[6]   + dvx*B1.z;
    h[7]  = __expf(dvt*An[7])*h[7]   + dvx*B1.w;
    h[8]  = __expf(dvt*An[8])*h[8]   + dvx*B2.x;
    h[9]  = __expf(dvt*An[9])*h[9]   + dvx*B2.y;
    h[10] = __expf(dvt*An[10])*h[10] + dvx*B2.z;
    h[11] = __expf(dvt*An[11])*h[11] + dvx*B2.w;
    h[12] = __expf(dvt*An[12])*h[12] + dvx*B3.x;
    h[13] = __expf(dvt*An[13])*h[13] + dvx*B3.y;
    h[14] = __expf(dvt*An[14])*h[14] + dvx*B3.z;
    h[15] = __expf(dvt*An[15])*h[15] + dvx*B3.w;
  }
  size_t hbase = (((size_t)(b * NCHUNK + c) * D_INNER) + d) * 16;
  #pragma unroll
  for (int q = 0; q < 4; ++q) {
    float4 o = {h[q*4+0], h[q*4+1], h[q*4+2], h[q*4+3]};
    *(float4*)&Hbuf[hbase + q*4] = o;
  }
  Sbuf[((size_t)b * NCHUNK + c) * D_INNER + d] = Ssum;
}

__global__ __launch_bounds__(256) void scan_phase2(
    const float* __restrict__ alog, const float* __restrict__ Sbuf,
    float* __restrict__ Hbuf) {
  const int tid = threadIdx.x;
  const int n  = tid & 15;
  const int dl = tid >> 4;
  const int d  = blockIdx.x * 16 + dl;
  const int b  = blockIdx.y;
  const float An = -__expf(alog[d * 16 + n]);
  float h_run = 0.f;
  #pragma unroll 4
  for (int c = 0; c < NCHUNK; ++c) {
    size_t idx = (((size_t)(b * NCHUNK + c) * D_INNER) + d) * 16 + n;
    float hend = Hbuf[idx];
    float P = __expf(An * Sbuf[((size_t)b * NCHUNK + c) * D_INNER + d]);
    Hbuf[idx] = h_run;                     // h at chunk START
    h_run = P * h_run + hend;
  }
}

__global__ __launch_bounds__(256) void scan_phase3(
    const float* __restrict__ xs, const float* __restrict__ xar,
    const float* __restrict__ dlt, const float* __restrict__ Bmat,
    const float* __restrict__ Cmat, const float* __restrict__ dtw,
    const float* __restrict__ dtb, const float* __restrict__ alog,
    const float* __restrict__ Dvec, const float* __restrict__ Hbuf,
    unsigned short* __restrict__ ybf) {
  __shared__ float dltS[CHUNK][16];
  __shared__ float BS[CHUNK][16];
  __shared__ float CS[CHUNK][16];
  const int tid = threadIdx.x;
  const int c   = blockIdx.y;
  const int b   = blockIdx.z;
  const int d   = blockIdx.x * 256 + tid;
  const int row0 = b * SEQ + c * CHUNK;
  {
    int e = tid * 2;
    int tt = e >> 4, r = e & 15;
    *(float2*)&dltS[tt][r] = *(const float2*)&dlt[(row0 + tt) * 16 + r];
    *(float2*)&BS[tt][r]   = *(const float2*)&Bmat[(row0 + tt) * 16 + r];
    *(float2*)&CS[tt][r]   = *(const float2*)&Cmat[(row0 + tt) * 16 + r];
  }
  float dtwr[16], An[16];
  #pragma unroll
  for (int q = 0; q < 4; ++q) {
    float4 w4 = *(const float4*)&dtw[d * 16 + q * 4];
    dtwr[q*4+0] = w4.x; dtwr[q*4+1] = w4.y; dtwr[q*4+2] = w4.z; dtwr[q*4+3] = w4.w;
    float4 a4 = *(const float4*)&alog[d * 16 + q * 4];
    An[q*4+0] = -__expf(a4.x); An[q*4+1] = -__expf(a4.y);
    An[q*4+2] = -__expf(a4.z); An[q*4+3] = -__expf(a4.w);
  }
  const float dtbv = dtb[d];
  const float Dn   = Dvec[d];
  float h[16];
  {
    size_t hbase = (((size_t)(b * NCHUNK + c) * D_INNER) + d) * 16;
    #pragma unroll
    for (int q = 0; q < 4; ++q) {
      float4 hv = *(const float4*)&Hbuf[hbase + q*4];
      h[q*4+0] = hv.x; h[q*4+1] = hv.y; h[q*4+2] = hv.z; h[q*4+3] = hv.w;
    }
  }
  float xv[CHUNK], rv[CHUNK];
  #pragma unroll
  for (int tt = 0; tt < CHUNK; ++tt) {
    xv[tt] = xs[(size_t)(row0 + tt) * D_INNER + d];
    rv[tt] = xar[(size_t)(row0 + tt) * (2 * D_INNER) + D_INNER + d];
  }
  __syncthreads();
  float dv[CHUNK];
  #pragma unroll
  for (int tt = 0; tt < CHUNK; ++tt) {
    float s = dtbv;
    DELTA16(dltS, tt);
    dv[tt] = softplus_f(s);
  }
  #pragma unroll
  for (int tt = 0; tt < CHUNK; ++tt) {
    const float dvt = dv[tt];
    const float dvx = dvt * xv[tt];
    float4 B0 = *(const float4*)&BS[tt][0];
    float4 B1 = *(const float4*)&BS[tt][4];
    float4 B2 = *(const float4*)&BS[tt][8];
    float4 B3 = *(const float4*)&BS[tt][12];
    float4 C0 = *(const float4*)&CS[tt][0];
    float4 C1 = *(const float4*)&CS[tt][4];
    float4 C2 = *(const float4*)&CS[tt][8];
    float4 C3 = *(const float4*)&CS[tt][12];
    float y = 0.f;
    h[0]  = __expf(dvt*An[0])*h[0]   + dvx*B0.x;  y += h[0]*C0.x;
    h[1]  = __expf(dvt*An[1])*h[1]   + dvx*B0.y;  y += h[1]*C0.y;
    h[2]  = __expf(dvt*An[2])*h[2]   + dvx*B0.z;  y += h[2]*C0.z;
    h[3]  = __expf(dvt*An[3])*h[3]   + dvx*B0.w;  y += h[3]*C0.w;
    h[4]  = __expf(dvt*An[4])*h[4]   + dvx*B1.x;  y += h[4]*C1.x;
    h[5]  = __expf(dvt*An[5])*h[5]   + dvx*B1.y;  y += h[5]*C1.y;
    h[6]  = __expf(dvt*An[6])*h[6]   + dvx*B1.z;  y += h[6]*C1.z;
    h[7]  = __expf(dvt*An[7])*h[7]   + dvx*B1.w;  y += h[7]*C1.w;
    h[8]  = __expf(dvt*An[8])*h[8]   + dvx*B2.x;  y += h[8]*C2.x;
    h[9]  = __expf(dvt*An[9])*h[9]   + dvx*B2.y;  y += h[9]*C2.y;
    h[10] = __expf(dvt*An[10])*h[10] + dvx*B2.z;  y += h[10]*C2.z;
    h[11] = __expf(dvt*An[11])*h[11] + dvx*B2.w;  y += h[11]*C2.w;
    h[12] = __expf(dvt*An[12])*h[12] + dvx*B3.x;  y += h[12]*C3.x;
    h[13] = __expf(dvt*An[13])*h[13] + dvx*B3.y;  y += h[13]*C3.y;
    h[14] = __expf(dvt*An[14])*h[14] + dvx*B3.z;  y += h[14]*C3.z;
    h[15] = __expf(dvt*An[15])*h[15] + dvx*B3.w;  y += h[15]*C3.w;
    y += xv[tt] * Dn;
    const float r = rv[tt];
    const float v = y * (r * sigmoid_fast(r));
    ybf[(size_t)(row0 + tt) * D_INNER + d] = f2bf(v);
  }
}

// ---------------- launcher ----------------
extern "C" void kernel_launch(void* const* d_in, const int* in_sizes, int n_in,
                              void* d_out, int out_size, void* d_ws, size_t ws_size,
                              hipStream_t stream) {
  const float* x    = (const float*)d_in[0];
  const float* ipw  = (const float*)d_in[1];
  const float* ipb  = (const float*)d_in[2];
  const float* cw   = (const float*)d_in[3];
  const float* cb   = (const float*)d_in[4];
  const float* xpw  = (const float*)d_in[5];
  const float* xpb  = (const float*)d_in[6];
  const float* dtw  = (const float*)d_in[7];
  const float* dtb  = (const float*)d_in[8];
  const float* alog = (const float*)d_in[9];
  const float* Dv   = (const float*)d_in[10];
  const float* opw  = (const float*)d_in[11];
  const float* opb  = (const float*)d_in[12];
  float* out = (float*)d_out;

  char* ws = (char*)d_ws;
  size_t off = 0;
  auto alloc = [&](size_t bytes) {
    char* p = ws + off;
    off += (bytes + 255) & ~(size_t)255;
    return p;
  };
  unsigned short* xbf   = (unsigned short*)alloc((size_t)M_ROWS * D_MODEL * 2);       // 4 MB
  unsigned short* w1bf  = (unsigned short*)alloc((size_t)2 * D_INNER * D_MODEL * 2);  // 8 MB
  unsigned short* w2bf  = (unsigned short*)alloc((size_t)D_MODEL * D_INNER * 2);      // 4 MB
  unsigned short* xpwbf = (unsigned short*)alloc((size_t)48 * D_INNER * 2);           // 192 KB
  float* xar = (float*)alloc((size_t)M_ROWS * 2 * D_INNER * 4);                       // 32 MB
  float* xsb = (float*)alloc((size_t)M_ROWS * D_INNER * 4);                           // 16 MB
  float* dlt = (float*)alloc((size_t)M_ROWS * 16 * 4);
  float* Bm  = (float*)alloc((size_t)M_ROWS * 16 * 4);
  float* Cm  = (float*)alloc((size_t)M_ROWS * 16 * 4);
  unsigned short* ybf = (unsigned short*)alloc((size_t)M_ROWS * D_INNER * 2);         // 8 MB
  if (off > ws_size) return;
  // w1bf region (8 MB) is dead after gemm1; it is reused twice with disjoint liveness:
  //   xsbf (bf16 xs): written by conv, read by xproj_mfma   [conv -> xproj]
  //   Hbuf (f32):     written by phase1, read by phase2/3    [phase1 -> phase3]
  unsigned short* xsbf = w1bf;  // [2048,2048] bf16 = 8 MB exactly
  float* Hbuf = (float*)w1bf;   // [B][NCHUNK][D_INNER][16] f32 = 8 MB exactly
  float* Sbuf = (float*)xbf;    // xbf dead after gemm1; Sbuf = 512 KB

  // 1. casts (x, in_proj_w, out_proj_w, x_proj_w) — grid covers ranges exactly
  cast_all_kernel<<<8288, 256, 0, stream>>>(x, ipw, opw, xpw, xbf, w1bf, w2bf, xpwbf);
  // 2. in_proj
  gemm_bf16_nt<<<dim3(4096 / 128, 2048 / 128), 256, 0, stream>>>(
      (const __bf16*)xbf, (const __bf16*)w1bf, ipb, xar, M_ROWS, 2 * D_INNER, D_MODEL);
  // 3. conv + silu (f32 + bf16 outputs)
  conv_silu_kernel<<<4096, 256, 0, stream>>>(xar, cw, cb, xsb, xsbf);
  // 4. x_proj via MFMA
  xproj_mfma<<<M_ROWS / 128, 256, 0, stream>>>(
      (const __bf16*)xsbf, (const __bf16*)xpwbf, xpb, dlt, Bm, Cm);
  // 5. chunked scan (3 phases)
  scan_phase1<<<dim3(D_INNER / 256, NCHUNK, BATCH), 256, 0, stream>>>(
      xsb, dlt, Bm, dtw, dtb, alog, Hbuf, Sbuf);
  scan_phase2<<<dim3(D_INNER / 16, BATCH), 256, 0, stream>>>(alog, Sbuf, Hbuf);
  scan_phase3<<<dim3(D_INNER / 256, NCHUNK, BATCH), 256, 0, stream>>>(
      xsb, xar, dlt, Bm, Cm, dtw, dtb, alog, Dv, Hbuf, ybf);
  // 6. out_proj
  gemm_bf16_nt<<<dim3(1024 / 128, 2048 / 128), 256, 0, stream>>>(
      (const __bf16*)ybf, (const __bf16*)w2bf, opb, out, M_ROWS, D_MODEL, D_INNER);
}

// Round 8
// 297.341 us; speedup vs baseline: 1.7334x; 1.0315x over previous
//
#include <hip/hip_runtime.h>

// ---------------- problem constants ----------------
#define D_MODEL 1024
#define D_STATE 16
#define D_CONV  4
#define D_INNER 2048
#define DT_RANK 16
#define BATCH   2
#define SEQ     1024
#define M_ROWS  (BATCH*SEQ)   // 2048 rows
#define CHUNK   32            // timesteps per scan chunk
#define NCHUNK  (SEQ/CHUNK)   // 32 chunks

typedef __bf16 bf16x8 __attribute__((ext_vector_type(8)));
typedef float  f32x4  __attribute__((ext_vector_type(4)));

__device__ __forceinline__ unsigned short f2bf(float f) {
  unsigned u = __float_as_uint(f);
  u += 0x7fffu + ((u >> 16) & 1u);      // round-to-nearest-even
  return (unsigned short)(u >> 16);
}

__device__ __forceinline__ float sigmoid_fast(float v) {
  return 1.f / (1.f + __expf(-v));
}

__device__ __forceinline__ float softplus_f(float s) {
  return (s > 20.f) ? s : __logf(1.f + __expf(s));
}

// async global->LDS, 16B per lane; LDS dest is wave-uniform base + lane*16 [m97/m104]
__device__ __forceinline__ void gll16(const void* g, void* l) {
  __builtin_amdgcn_global_load_lds(
      (const __attribute__((address_space(1))) unsigned int*)g,
      (__attribute__((address_space(3))) unsigned int*)l, 16, 0, 0);
}

// ---------------- cast f32 -> bf16 (x, in_proj_w, out_proj_w, x_proj_w) ----------------
__global__ __launch_bounds__(256) void cast_all_kernel(
    const float* __restrict__ x, const float* __restrict__ w1, const float* __restrict__ w2,
    const float* __restrict__ xpw,
    unsigned short* __restrict__ xbf, unsigned short* __restrict__ w1bf,
    unsigned short* __restrict__ w2bf, unsigned short* __restrict__ xpwbf) {
  const int N0 = (M_ROWS * D_MODEL) / 4;        // 524288 float4
  const int N1 = (2 * D_INNER * D_MODEL) / 4;   // 1048576
  const int N2 = (D_MODEL * D_INNER) / 4;       // 524288
  int i = blockIdx.x * 256 + threadIdx.x;       // grid covers N0+N1+N2+N3 exactly
  const float* src; unsigned short* dst; int off;
  if (i < N0)                 { src = x;   dst = xbf;   off = i; }
  else if (i < N0 + N1)       { src = w1;  dst = w1bf;  off = i - N0; }
  else if (i < N0 + N1 + N2)  { src = w2;  dst = w2bf;  off = i - N0 - N1; }
  else                        { src = xpw; dst = xpwbf; off = i - N0 - N1 - N2; }
  float4 v = *(const float4*)(src + (size_t)off * 4);
  ushort4 o;
  o.x = f2bf(v.x); o.y = f2bf(v.y); o.z = f2bf(v.z); o.w = f2bf(v.w);
  *(ushort4*)(dst + (size_t)off * 4) = o;
}

// ---------------- bf16 MFMA GEMM with global_load_lds staging (m97 structure) ----------
// NT: C[M,N] = A[M,K] @ B[N,K]^T + bias[N].
// Tile BM x 128, BK=32, 4 waves as 2x2; wave tile (BM/2) x 64 = MR x 4 fragments.
// LDS is LINEAR [rows][32] (required by global_load_lds); 8-way ds_read conflicts
// accepted per m97/m98 precedent (874 TF with 1.7e7 conflicts).
template<int BM>
__global__ __launch_bounds__(256) void gemm_gll(
    const __bf16* __restrict__ A, const __bf16* __restrict__ B,
    const float* __restrict__ bias, float* __restrict__ C,
    int M, int N, int K) {
  constexpr int MR = BM / 32;          // M fragments per wave (2 or 4)
  __shared__ __bf16 As[BM][32];
  __shared__ __bf16 Bs[128][32];
  const int tid  = threadIdx.x;
  const int lane = tid & 63;
  const int w    = tid >> 6;
  const int wr   = w >> 1, wc = w & 1;
  const int rowBase = blockIdx.y * BM;
  const int colBase = blockIdx.x * 128;

  f32x4 acc[MR][4];
  #pragma unroll
  for (int i = 0; i < MR; ++i)
    #pragma unroll
    for (int j = 0; j < 4; ++j) { f32x4 z = {0.f,0.f,0.f,0.f}; acc[i][j] = z; }

  const int srow = lane >> 2;        // staging row within 16-row group
  const int sk   = (lane & 3) * 8;   // staging k element offset
  const int fr   = lane & 15;
  const int fk   = (lane >> 4) * 8;

  for (int k0 = 0; k0 < K; k0 += 32) {
    // stage A (BM x 32): BM/64 instrs per wave, each 16 rows x 64B = 1024B
    #pragma unroll
    for (int i = 0; i < BM / 64; ++i) {
      const int r0 = w * (BM / 4) + i * 16;
      gll16(A + (size_t)(rowBase + r0 + srow) * K + k0 + sk, &As[r0][0]);
    }
    // stage B (128 x 32): 2 instrs per wave
    #pragma unroll
    for (int i = 0; i < 2; ++i) {
      const int r0 = w * 32 + i * 16;
      gll16(B + (size_t)(colBase + r0 + srow) * K + k0 + sk, &Bs[r0][0]);
    }
    __syncthreads();   // compiler drains vmcnt before s_barrier

    bf16x8 af[MR], bfr[4];
    #pragma unroll
    for (int mm = 0; mm < MR; ++mm)
      af[mm] = *(const bf16x8*)&As[wr * (BM / 2) + mm * 16 + fr][fk];
    #pragma unroll
    for (int nn = 0; nn < 4; ++nn)
      bfr[nn] = *(const bf16x8*)&Bs[wc * 64 + nn * 16 + fr][fk];
    #pragma unroll
    for (int mm = 0; mm < MR; ++mm)
      #pragma unroll
      for (int nn = 0; nn < 4; ++nn)
        acc[mm][nn] = __builtin_amdgcn_mfma_f32_16x16x32_bf16(af[mm], bfr[nn], acc[mm][nn], 0, 0, 0);
    __syncthreads();
  }

  // epilogue: C/D layout col=lane&15, row=(lane>>4)*4+reg  [verified m89/m91]
  #pragma unroll
  for (int nn = 0; nn < 4; ++nn) {
    int col = colBase + wc * 64 + nn * 16 + fr;
    float bv = bias[col];
    #pragma unroll
    for (int mm = 0; mm < MR; ++mm) {
      int row0 = rowBase + wr * (BM / 2) + mm * 16 + (lane >> 4) * 4;
      #pragma unroll
      for (int r = 0; r < 4; ++r)
        C[(size_t)(row0 + r) * N + col] = acc[mm][nn][r] + bv;
    }
  }
}

// ---------------- causal depthwise conv (k=4) + bias + SiLU (emit f32 + bf16) ----------------
__global__ __launch_bounds__(256) void conv_silu_kernel(
    const float* __restrict__ xar, const float* __restrict__ cw,
    const float* __restrict__ cb, float* __restrict__ xs,
    unsigned short* __restrict__ xsbf) {
  int idx = blockIdx.x * 256 + threadIdx.x;
  int m  = idx >> 9;
  int d4 = (idx & 511) << 2;
  int t  = m & (SEQ - 1);
  float a0 = 0.f, a1 = 0.f, a2 = 0.f, a3 = 0.f;
  #pragma unroll
  for (int j = 0; j < 4; ++j) {
    int tt = t - 3 + j;
    if (tt < 0) continue;
    const float4 v = *(const float4*)&xar[(size_t)(m - 3 + j) * (2 * D_INNER) + d4];
    a0 += v.x * cw[(d4 + 0) * 4 + j];
    a1 += v.y * cw[(d4 + 1) * 4 + j];
    a2 += v.z * cw[(d4 + 2) * 4 + j];
    a3 += v.w * cw[(d4 + 3) * 4 + j];
  }
  a0 += cb[d4 + 0]; a1 += cb[d4 + 1]; a2 += cb[d4 + 2]; a3 += cb[d4 + 3];
  float4 o;
  o.x = a0 * sigmoid_fast(a0);
  o.y = a1 * sigmoid_fast(a1);
  o.z = a2 * sigmoid_fast(a2);
  o.w = a3 * sigmoid_fast(a3);
  *(float4*)&xs[(size_t)m * D_INNER + d4] = o;
  ushort4 ob;
  ob.x = f2bf(o.x); ob.y = f2bf(o.y); ob.z = f2bf(o.z); ob.w = f2bf(o.w);
  *(ushort4*)&xsbf[(size_t)m * D_INNER + d4] = ob;
}

// ---------------- x_proj via MFMA: [2048,48] = xs_bf @ xpw_bf^T + b; split dlt/B/C ----------------
__global__ __launch_bounds__(256) void xproj_mfma(
    const __bf16* __restrict__ A, const __bf16* __restrict__ B,
    const float* __restrict__ xpb,
    float* __restrict__ dlt, float* __restrict__ Bm, float* __restrict__ Cm) {
  __shared__ __bf16 As[128][40];
  __shared__ __bf16 Bs[48][40];
  const int tid  = threadIdx.x;
  const int lane = tid & 63;
  const int w    = tid >> 6;                    // wave: rows w*32 .. w*32+31
  const int rowBase = blockIdx.x * 128;

  f32x4 acc[2][3];
  #pragma unroll
  for (int i = 0; i < 2; ++i)
    #pragma unroll
    for (int j = 0; j < 3; ++j) {
      f32x4 z = {0.f, 0.f, 0.f, 0.f};
      acc[i][j] = z;
    }

  const int sr = tid >> 2;          // 0..63
  const int ss = (tid & 3) * 8;     // 0,8,16,24
  const int fr = lane & 15;
  const int fk = (lane >> 4) * 8;

  for (int k0 = 0; k0 < D_INNER; k0 += 32) {
    const __bf16* Ap = A + (size_t)(rowBase + sr) * D_INNER + k0 + ss;
    *(bf16x8*)&As[sr][ss]      = *(const bf16x8*)Ap;
    *(bf16x8*)&As[sr + 64][ss] = *(const bf16x8*)(Ap + (size_t)64 * D_INNER);
    if (tid < 192)
      *(bf16x8*)&Bs[tid >> 2][ss] = *(const bf16x8*)(B + (size_t)(tid >> 2) * D_INNER + k0 + ss);
    __syncthreads();

    bf16x8 af[2], bfr[3];
    #pragma unroll
    for (int mm = 0; mm < 2; ++mm)
      af[mm] = *(const bf16x8*)&As[w * 32 + mm * 16 + fr][fk];
    #pragma unroll
    for (int nn = 0; nn < 3; ++nn)
      bfr[nn] = *(const bf16x8*)&Bs[nn * 16 + fr][fk];
    #pragma unroll
    for (int mm = 0; mm < 2; ++mm)
      #pragma unroll
      for (int nn = 0; nn < 3; ++nn)
        acc[mm][nn] = __builtin_amdgcn_mfma_f32_16x16x32_bf16(af[mm], bfr[nn], acc[mm][nn], 0, 0, 0);
    __syncthreads();
  }

  // C/D layout: col = lane&15, row = (lane>>4)*4 + reg
  const int c16 = lane & 15;
  #pragma unroll
  for (int nn = 0; nn < 3; ++nn) {
    float bv = xpb[nn * 16 + c16];
    float* dst = (nn == 0) ? dlt : (nn == 1) ? Bm : Cm;
    #pragma unroll
    for (int mm = 0; mm < 2; ++mm) {
      int row0 = rowBase + w * 32 + mm * 16 + (lane >> 4) * 4;
      #pragma unroll
      for (int r = 0; r < 4; ++r)
        dst[(size_t)(row0 + r) * 16 + c16] = acc[mm][nn][r] + bv;
    }
  }
}

// ======================= chunked parallel selective scan =======================
// h_t = exp(dv_t*A)*h_{t-1} + (dv_t*x_t)*B_t ; prefix decay = exp(A * cumsum(dv)).
// Phase1: per-chunk local scan from h=0 -> Hbuf[b][c][d][16] = local h_end, Sbuf = sum(dv).
// Phase2: sequential combine over 32 chunks; Hbuf becomes TRUE h at chunk START (in-place).
// Phase3: replay each chunk from true h_start; fuse y, D-skip, gate, bf16 cast.

#define DELTA16(sarr, ttq)                                                       \
  {                                                                              \
    float4 q0 = *(const float4*)&sarr[ttq][0];                                   \
    float4 q1 = *(const float4*)&sarr[ttq][4];                                   \
    float4 q2 = *(const float4*)&sarr[ttq][8];                                   \
    float4 q3 = *(const float4*)&sarr[ttq][12];                                  \
    s += q0.x*dtwr[0] + q0.y*dtwr[1] + q0.z*dtwr[2] + q0.w*dtwr[3];              \
    s += q1.x*dtwr[4] + q1.y*dtwr[5] + q1.z*dtwr[6] + q1.w*dtwr[7];              \
    s += q2.x*dtwr[8] + q2.y*dtwr[9] + q2.z*dtwr[10] + q2.w*dtwr[11];            \
    s += q3.x*dtwr[12] + q3.y*dtwr[13] + q3.z*dtwr[14] + q3.w*dtwr[15];          \
  }

__global__ __launch_bounds__(256) void scan_phase1(
    const float* __restrict__ xs, const float* __restrict__ dlt,
    const float* __restrict__ Bmat, const float* __restrict__ dtw,
    const float* __restrict__ dtb, const float* __restrict__ alog,
    float* __restrict__ Hbuf, float* __restrict__ Sbuf) {
  __shared__ float dltS[CHUNK][16];
  __shared__ float BS[CHUNK][16];
  const int tid = threadIdx.x;
  const int c   = blockIdx.y;
  const int b   = blockIdx.z;
  const int d   = blockIdx.x * 256 + tid;
  const int row0 = b * SEQ + c * CHUNK;
  {
    int e = tid * 2;
    int tt = e >> 4, r = e & 15;
    *(float2*)&dltS[tt][r] = *(const float2*)&dlt[(row0 + tt) * 16 + r];
    *(float2*)&BS[tt][r]   = *(const float2*)&Bmat[(row0 + tt) * 16 + r];
  }
  float dtwr[16], An[16];
  #pragma unroll
  for (int q = 0; q < 4; ++q) {
    float4 w4 = *(const float4*)&dtw[d * 16 + q * 4];
    dtwr[q*4+0] = w4.x; dtwr[q*4+1] = w4.y; dtwr[q*4+2] = w4.z; dtwr[q*4+3] = w4.w;
    float4 a4 = *(const float4*)&alog[d * 16 + q * 4];
    An[q*4+0] = -__expf(a4.x); An[q*4+1] = -__expf(a4.y);
    An[q*4+2] = -__expf(a4.z); An[q*4+3] = -__expf(a4.w);
  }
  const float dtbv = dtb[d];
  float xv[CHUNK];
  #pragma unroll
  for (int tt = 0; tt < CHUNK; ++tt)
    xv[tt] = xs[(size_t)(row0 + tt) * D_INNER + d];
  __syncthreads();
  float dv[CHUNK];
  #pragma unroll
  for (int tt = 0; tt < CHUNK; ++tt) {
    float s = dtbv;
    DELTA16(dltS, tt);
    dv[tt] = softplus_f(s);
  }
  float h[16];
  #pragma unroll
  for (int n = 0; n < 16; ++n) h[n] = 0.f;
  float Ssum = 0.f;
  #pragma unroll
  for (int tt = 0; tt < CHUNK; ++tt) {
    const float dvt = dv[tt];
    Ssum += dvt;
    const float dvx = dvt * xv[tt];
    float4 B0 = *(const float4*)&BS[tt][0];
    float4 B1 = *(const float4*)&BS[tt][4];
    float4 B2 = *(const float4*)&BS[tt][8];
    float4 B3 = *(const float4*)&BS[tt][12];
    h[0]  = __expf(dvt*An[0])*h[0]   + dvx*B0.x;
    h[1]  = __expf(dvt*An[1])*h[1]   + dvx*B0.y;
    h[2]  = __expf(dvt*An[2])*h[2]   + dvx*B0.z;
    h[3]  = __expf(dvt*An[3])*h[3]   + dvx*B0.w;
    h[4]  = __expf(dvt*An[4])*h[4]   + dvx*B1.x;
    h[5]  = __expf(dvt*An[5])*h[5]   + dvx*B1.y;
    h[6]  = __expf(dvt*An[6])*h[6]   + dvx*B1.z;
    h[7]  = __expf(dvt*An[7])*h[7]   + dvx*B1.w;
    h[8]  = __expf(dvt*An[8])*h[8]   + dvx*B2.x;
    h[9]  = __expf(dvt*An[9])*h[9]   + dvx*B2.y;
    h[10] = __expf(dvt*An[10])*h[10] + dvx*B2.z;
    h[11] = __expf(dvt*An[11])*h[11] + dvx*B2.w;
    h[12] = __expf(dvt*An[12])*h[12] + dvx*B3.x;
    h[13] = __expf(dvt*An[13])*h[13] + dvx*B3.y;
    h[14] = __expf(dvt*An[14])*h[14] + dvx*B3.z;
    h[15] = __expf(dvt*An[15])*h[15] + dvx*B3.w;
  }
  size_t hbase = (((size_t)(b * NCHUNK + c) * D_INNER) + d) * 16;
  #pragma unroll
  for (int q = 0; q < 4; ++q) {
    float4 o = {h[q*4+0], h[q*4+1], h[q*4+2], h[q*4+3]};
    *(float4*)&Hbuf[hbase + q*4] = o;
  }
  Sbuf[((size_t)b * NCHUNK + c) * D_INNER + d] = Ssum;
}

__global__ __launch_bounds__(256) void scan_phase2(
    const float* __restrict__ alog, const float* __restrict__ Sbuf,
    float* __restrict__ Hbuf) {
  const int tid = threadIdx.x;
  const int n  = tid & 15;
  const int dl = tid >> 4;
  const int d  = blockIdx.x * 16 + dl;
  const int b  = blockIdx.y;
  const float An = -__expf(alog[d * 16 + n]);
  float h_run = 0.f;
  #pragma unroll 4
  for (int c = 0; c < NCHUNK; ++c) {
    size_t idx = (((size_t)(b * NCHUNK + c) * D_INNER) + d) * 16 + n;
    float hend = Hbuf[idx];
    float P = __expf(An * Sbuf[((size_t)b * NCHUNK + c) * D_INNER + d]);
    Hbuf[idx] = h_run;                     // h at chunk START
    h_run = P * h_run + hend;
  }
}

__global__ __launch_bounds__(256) void scan_phase3(
    const float* __restrict__ xs, const float* __restrict__ xar,
    const float* __restrict__ dlt, const float* __restrict__ Bmat,
    const float* __restrict__ Cmat, const float* __restrict__ dtw,
    const float* __restrict__ dtb, const float* __restrict__ alog,
    const float* __restrict__ Dvec, const float* __restrict__ Hbuf,
    unsigned short* __restrict__ ybf) {
  __shared__ float dltS[CHUNK][16];
  __shared__ float BS[CHUNK][16];
  __shared__ float CS[CHUNK][16];
  const int tid = threadIdx.x;
  const int c   = blockIdx.y;
  const int b   = blockIdx.z;
  const int d   = blockIdx.x * 256 + tid;
  const int row0 = b * SEQ + c * CHUNK;
  {
    int e = tid * 2;
    int tt = e >> 4, r = e & 15;
    *(float2*)&dltS[tt][r] = *(const float2*)&dlt[(row0 + tt) * 16 + r];
    *(float2*)&BS[tt][r]   = *(const float2*)&Bmat[(row0 + tt) * 16 + r];
    *(float2*)&CS[tt][r]   = *(const float2*)&Cmat[(row0 + tt) * 16 + r];
  }
  float dtwr[16], An[16];
  #pragma unroll
  for (int q = 0; q < 4; ++q) {
    float4 w4 = *(const float4*)&dtw[d * 16 + q * 4];
    dtwr[q*4+0] = w4.x; dtwr[q*4+1] = w4.y; dtwr[q*4+2] = w4.z; dtwr[q*4+3] = w4.w;
    float4 a4 = *(const float4*)&alog[d * 16 + q * 4];
    An[q*4+0] = -__expf(a4.x); An[q*4+1] = -__expf(a4.y);
    An[q*4+2] = -__expf(a4.z); An[q*4+3] = -__expf(a4.w);
  }
  const float dtbv = dtb[d];
  const float Dn   = Dvec[d];
  float h[16];
  {
    size_t hbase = (((size_t)(b * NCHUNK + c) * D_INNER) + d) * 16;
    #pragma unroll
    for (int q = 0; q < 4; ++q) {
      float4 hv = *(const float4*)&Hbuf[hbase + q*4];
      h[q*4+0] = hv.x; h[q*4+1] = hv.y; h[q*4+2] = hv.z; h[q*4+3] = hv.w;
    }
  }
  float xv[CHUNK], rv[CHUNK];
  #pragma unroll
  for (int tt = 0; tt < CHUNK; ++tt) {
    xv[tt] = xs[(size_t)(row0 + tt) * D_INNER + d];
    rv[tt] = xar[(size_t)(row0 + tt) * (2 * D_INNER) + D_INNER + d];
  }
  __syncthreads();
  float dv[CHUNK];
  #pragma unroll
  for (int tt = 0; tt < CHUNK; ++tt) {
    float s = dtbv;
    DELTA16(dltS, tt);
    dv[tt] = softplus_f(s);
  }
  #pragma unroll
  for (int tt = 0; tt < CHUNK; ++tt) {
    const float dvt = dv[tt];
    const float dvx = dvt * xv[tt];
    float4 B0 = *(const float4*)&BS[tt][0];
    float4 B1 = *(const float4*)&BS[tt][4];
    float4 B2 = *(const float4*)&BS[tt][8];
    float4 B3 = *(const float4*)&BS[tt][12];
    float4 C0 = *(const float4*)&CS[tt][0];
    float4 C1 = *(const float4*)&CS[tt][4];
    float4 C2 = *(const float4*)&CS[tt][8];
    float4 C3 = *(const float4*)&CS[tt][12];
    float y = 0.f;
    h[0]  = __expf(dvt*An[0])*h[0]   + dvx*B0.x;  y += h[0]*C0.x;
    h[1]  = __expf(dvt*An[1])*h[1]   + dvx*B0.y;  y += h[1]*C0.y;
    h[2]  = __expf(dvt*An[2])*h[2]   + dvx*B0.z;  y += h[2]*C0.z;
    h[3]  = __expf(dvt*An[3])*h[3]   + dvx*B0.w;  y += h[3]*C0.w;
    h[4]  = __expf(dvt*An[4])*h[4]   + dvx*B1.x;  y += h[4]*C1.x;
    h[5]  = __expf(dvt*An[5])*h[5]   + dvx*B1.y;  y += h[5]*C1.y;
    h[6]  = __expf(dvt*An[6])*h[6]   + dvx*B1.z;  y += h[6]*C1.z;
    h[7]  = __expf(dvt*An[7])*h[7]   + dvx*B1.w;  y += h[7]*C1.w;
    h[8]  = __expf(dvt*An[8])*h[8]   + dvx*B2.x;  y += h[8]*C2.x;
    h[9]  = __expf(dvt*An[9])*h[9]   + dvx*B2.y;  y += h[9]*C2.y;
    h[10] = __expf(dvt*An[10])*h[10] + dvx*B2.z;  y += h[10]*C2.z;
    h[11] = __expf(dvt*An[11])*h[11] + dvx*B2.w;  y += h[11]*C2.w;
    h[12] = __expf(dvt*An[12])*h[12] + dvx*B3.x;  y += h[12]*C3.x;
    h[13] = __expf(dvt*An[13])*h[13] + dvx*B3.y;  y += h[13]*C3.y;
    h[14] = __expf(dvt*An[14])*h[14] + dvx*B3.z;  y += h[14]*C3.z;
    h[15] = __expf(dvt*An[15])*h[15] + dvx*B3.w;  y += h[15]*C3.w;
    y += xv[tt] * Dn;
    const float r = rv[tt];
    const float v = y * (r * sigmoid_fast(r));
    ybf[(size_t)(row0 + tt) * D_INNER + d] = f2bf(v);
  }
}

// ---------------- launcher ----------------
extern "C" void kernel_launch(void* const* d_in, const int* in_sizes, int n_in,
                              void* d_out, int out_size, void* d_ws, size_t ws_size,
                              hipStream_t stream) {
  const float* x    = (const float*)d_in[0];
  const float* ipw  = (const float*)d_in[1];
  const float* ipb  = (const float*)d_in[2];
  const float* cw   = (const float*)d_in[3];
  const float* cb   = (const float*)d_in[4];
  const float* xpw  = (const float*)d_in[5];
  const float* xpb  = (const float*)d_in[6];
  const float* dtw  = (const float*)d_in[7];
  const float* dtb  = (const float*)d_in[8];
  const float* alog = (const float*)d_in[9];
  const float* Dv   = (const float*)d_in[10];
  const float* opw  = (const float*)d_in[11];
  const float* opb  = (const float*)d_in[12];
  float* out = (float*)d_out;

  char* ws = (char*)d_ws;
  size_t off = 0;
  auto alloc = [&](size_t bytes) {
    char* p = ws + off;
    off += (bytes + 255) & ~(size_t)255;
    return p;
  };
  unsigned short* xbf   = (unsigned short*)alloc((size_t)M_ROWS * D_MODEL * 2);       // 4 MB
  unsigned short* w1bf  = (unsigned short*)alloc((size_t)2 * D_INNER * D_MODEL * 2);  // 8 MB
  unsigned short* w2bf  = (unsigned short*)alloc((size_t)D_MODEL * D_INNER * 2);      // 4 MB
  unsigned short* xpwbf = (unsigned short*)alloc((size_t)48 * D_INNER * 2);           // 192 KB
  float* xar = (float*)alloc((size_t)M_ROWS * 2 * D_INNER * 4);                       // 32 MB
  float* xsb = (float*)alloc((size_t)M_ROWS * D_INNER * 4);                           // 16 MB
  float* dlt = (float*)alloc((size_t)M_ROWS * 16 * 4);
  float* Bm  = (float*)alloc((size_t)M_ROWS * 16 * 4);
  float* Cm  = (float*)alloc((size_t)M_ROWS * 16 * 4);
  unsigned short* ybf = (unsigned short*)alloc((size_t)M_ROWS * D_INNER * 2);         // 8 MB
  if (off > ws_size) return;
  // w1bf region (8 MB) is dead after gemm1; it is reused twice with disjoint liveness:
  //   xsbf (bf16 xs): written by conv, read by xproj_mfma   [conv -> xproj]
  //   Hbuf (f32):     written by phase1, read by phase2/3    [phase1 -> phase3]
  unsigned short* xsbf = w1bf;  // [2048,2048] bf16 = 8 MB exactly
  float* Hbuf = (float*)w1bf;   // [B][NCHUNK][D_INNER][16] f32 = 8 MB exactly
  float* Sbuf = (float*)xbf;    // xbf dead after gemm1; Sbuf = 512 KB

  // 1. casts (x, in_proj_w, out_proj_w, x_proj_w)
  cast_all_kernel<<<8288, 256, 0, stream>>>(x, ipw, opw, xpw, xbf, w1bf, w2bf, xpwbf);
  // 2. in_proj: 128x128 tiles, 512 wgs
  gemm_gll<128><<<dim3(4096 / 128, 2048 / 128), 256, 0, stream>>>(
      (const __bf16*)xbf, (const __bf16*)w1bf, ipb, xar, M_ROWS, 2 * D_INNER, D_MODEL);
  // 3. conv + silu (f32 + bf16 outputs)
  conv_silu_kernel<<<4096, 256, 0, stream>>>(xar, cw, cb, xsb, xsbf);
  // 4. x_proj via MFMA
  xproj_mfma<<<M_ROWS / 128, 256, 0, stream>>>(
      (const __bf16*)xsbf, (const __bf16*)xpwbf, xpb, dlt, Bm, Cm);
  // 5. chunked scan (3 phases)
  scan_phase1<<<dim3(D_INNER / 256, NCHUNK, BATCH), 256, 0, stream>>>(
      xsb, dlt, Bm, dtw, dtb, alog, Hbuf, Sbuf);
  scan_phase2<<<dim3(D_INNER / 16, BATCH), 256, 0, stream>>>(alog, Sbuf, Hbuf);
  scan_phase3<<<dim3(D_INNER / 256, NCHUNK, BATCH), 256, 0, stream>>>(
      xsb, xar, dlt, Bm, Cm, dtw, dtb, alog, Dv, Hbuf, ybf);
  // 6. out_proj: 64x128 tiles -> 256 wgs (fills all CUs; was 128 wgs at BM=128)
  gemm_gll<64><<<dim3(1024 / 128, 2048 / 64), 256, 0, stream>>>(
      (const __bf16*)ybf, (const __bf16*)w2bf, opb, out, M_ROWS, D_MODEL, D_INNER);
}

// Round 9
// 278.886 us; speedup vs baseline: 1.8482x; 1.0662x over previous
//
#include <hip/hip_runtime.h>

// ---------------- problem constants ----------------
#define D_MODEL 1024
#define D_STATE 16
#define D_CONV  4
#define D_INNER 2048
#define DT_RANK 16
#define BATCH   2
#define SEQ     1024
#define M_ROWS  (BATCH*SEQ)   // 2048 rows
#define CHUNK   32            // timesteps per scan chunk
#define NCHUNK  (SEQ/CHUNK)   // 32 chunks

typedef __bf16 bf16x8 __attribute__((ext_vector_type(8)));
typedef float  f32x4  __attribute__((ext_vector_type(4)));

__device__ __forceinline__ unsigned short f2bf(float f) {
  unsigned u = __float_as_uint(f);
  u += 0x7fffu + ((u >> 16) & 1u);      // round-to-nearest-even
  return (unsigned short)(u >> 16);
}

__device__ __forceinline__ float sigmoid_fast(float v) {
  return 1.f / (1.f + __expf(-v));
}

__device__ __forceinline__ float softplus_f(float s) {
  return (s > 20.f) ? s : __logf(1.f + __expf(s));
}

// async global->LDS, 16B per lane; LDS dest is wave-uniform base + lane*16 [m97/m104]
__device__ __forceinline__ void gll16(const void* g, void* l) {
  __builtin_amdgcn_global_load_lds(
      (const __attribute__((address_space(1))) unsigned int*)g,
      (__attribute__((address_space(3))) unsigned int*)l, 16, 0, 0);
}

// epilogue store helpers (f32 or bf16 C)
__device__ __forceinline__ void storeC(float v, float* p)          { *p = v; }
__device__ __forceinline__ void storeC(float v, unsigned short* p) { *p = f2bf(v); }

// ---------------- cast f32 -> bf16 (x, in_proj_w, out_proj_w, x_proj_w) ----------------
__global__ __launch_bounds__(256) void cast_all_kernel(
    const float* __restrict__ x, const float* __restrict__ w1, const float* __restrict__ w2,
    const float* __restrict__ xpw,
    unsigned short* __restrict__ xbf, unsigned short* __restrict__ w1bf,
    unsigned short* __restrict__ w2bf, unsigned short* __restrict__ xpwbf) {
  const int N0 = (M_ROWS * D_MODEL) / 4;        // 524288 float4
  const int N1 = (2 * D_INNER * D_MODEL) / 4;   // 1048576
  const int N2 = (D_MODEL * D_INNER) / 4;       // 524288
  int i = blockIdx.x * 256 + threadIdx.x;       // grid covers N0+N1+N2+N3 exactly
  const float* src; unsigned short* dst; int off;
  if (i < N0)                 { src = x;   dst = xbf;   off = i; }
  else if (i < N0 + N1)       { src = w1;  dst = w1bf;  off = i - N0; }
  else if (i < N0 + N1 + N2)  { src = w2;  dst = w2bf;  off = i - N0 - N1; }
  else                        { src = xpw; dst = xpwbf; off = i - N0 - N1 - N2; }
  float4 v = *(const float4*)(src + (size_t)off * 4);
  ushort4 o;
  o.x = f2bf(v.x); o.y = f2bf(v.y); o.z = f2bf(v.z); o.w = f2bf(v.w);
  *(ushort4*)(dst + (size_t)off * 4) = o;
}

// ---------------- bf16 MFMA GEMM with global_load_lds staging (m97 structure) ----------
// NT: C[M,N] = A[M,K] @ B[N,K]^T + bias[N]. CT = float or unsigned short (bf16 out).
template<int BM, typename CT>
__global__ __launch_bounds__(256) void gemm_gll(
    const __bf16* __restrict__ A, const __bf16* __restrict__ B,
    const float* __restrict__ bias, CT* __restrict__ C,
    int M, int N, int K) {
  constexpr int MR = BM / 32;          // M fragments per wave (2 or 4)
  __shared__ __bf16 As[BM][32];
  __shared__ __bf16 Bs[128][32];
  const int tid  = threadIdx.x;
  const int lane = tid & 63;
  const int w    = tid >> 6;
  const int wr   = w >> 1, wc = w & 1;
  const int rowBase = blockIdx.y * BM;
  const int colBase = blockIdx.x * 128;

  f32x4 acc[MR][4];
  #pragma unroll
  for (int i = 0; i < MR; ++i)
    #pragma unroll
    for (int j = 0; j < 4; ++j) { f32x4 z = {0.f,0.f,0.f,0.f}; acc[i][j] = z; }

  const int srow = lane >> 2;        // staging row within 16-row group
  const int sk   = (lane & 3) * 8;   // staging k element offset
  const int fr   = lane & 15;
  const int fk   = (lane >> 4) * 8;

  for (int k0 = 0; k0 < K; k0 += 32) {
    #pragma unroll
    for (int i = 0; i < BM / 64; ++i) {
      const int r0 = w * (BM / 4) + i * 16;
      gll16(A + (size_t)(rowBase + r0 + srow) * K + k0 + sk, &As[r0][0]);
    }
    #pragma unroll
    for (int i = 0; i < 2; ++i) {
      const int r0 = w * 32 + i * 16;
      gll16(B + (size_t)(colBase + r0 + srow) * K + k0 + sk, &Bs[r0][0]);
    }
    __syncthreads();

    bf16x8 af[MR], bfr[4];
    #pragma unroll
    for (int mm = 0; mm < MR; ++mm)
      af[mm] = *(const bf16x8*)&As[wr * (BM / 2) + mm * 16 + fr][fk];
    #pragma unroll
    for (int nn = 0; nn < 4; ++nn)
      bfr[nn] = *(const bf16x8*)&Bs[wc * 64 + nn * 16 + fr][fk];
    #pragma unroll
    for (int mm = 0; mm < MR; ++mm)
      #pragma unroll
      for (int nn = 0; nn < 4; ++nn)
        acc[mm][nn] = __builtin_amdgcn_mfma_f32_16x16x32_bf16(af[mm], bfr[nn], acc[mm][nn], 0, 0, 0);
    __syncthreads();
  }

  // epilogue: C/D layout col=lane&15, row=(lane>>4)*4+reg  [verified m89/m91]
  #pragma unroll
  for (int nn = 0; nn < 4; ++nn) {
    int col = colBase + wc * 64 + nn * 16 + fr;
    float bv = bias[col];
    #pragma unroll
    for (int mm = 0; mm < MR; ++mm) {
      int row0 = rowBase + wr * (BM / 2) + mm * 16 + (lane >> 4) * 4;
      #pragma unroll
      for (int r = 0; r < 4; ++r)
        storeC(acc[mm][nn][r] + bv, &C[(size_t)(row0 + r) * N + col]);
    }
  }
}

// ---------------- causal depthwise conv (k=4) + bias + SiLU ----------------
// reads bf16 xar (xs branch, cols 0..2047), writes bf16 xs ONLY (8 MB).
__global__ __launch_bounds__(256) void conv_silu_kernel(
    const unsigned short* __restrict__ xar, const float* __restrict__ cw,
    const float* __restrict__ cb, unsigned short* __restrict__ xsbf) {
  int idx = blockIdx.x * 256 + threadIdx.x;     // one bf16x8 of d per thread
  int m  = idx >> 8;                            // row (b*1024 + t)
  int d8 = (idx & 255) << 3;                    // d offset (0..2040)
  int t  = m & (SEQ - 1);
  const __bf16* xarb = (const __bf16*)xar;

  float4 cwl[8];
  const float4* cw4 = (const float4*)cw;        // cw[d][0..3] contiguous
  #pragma unroll
  for (int e = 0; e < 8; ++e) cwl[e] = cw4[d8 + e];

  float acc[8];
  #pragma unroll
  for (int e = 0; e < 8; ++e) acc[e] = cb[d8 + e];

  #pragma unroll
  for (int j = 0; j < 4; ++j) {
    int tt = t - 3 + j;
    if (tt < 0) continue;                       // causal left zero-pad (per batch)
    bf16x8 v = *(const bf16x8*)&xarb[(size_t)(m - 3 + j) * (2 * D_INNER) + d8];
    const float* cj = (const float*)cwl;        // cwl[e] components: [e].x/.y/.z/.w
    #pragma unroll
    for (int e = 0; e < 8; ++e)
      acc[e] += (float)v[e] * cj[e * 4 + j];
  }
  unsigned short o[8];
  #pragma unroll
  for (int e = 0; e < 8; ++e) {
    float s = acc[e] * sigmoid_fast(acc[e]);
    o[e] = f2bf(s);
  }
  *(ushort4*)&xsbf[(size_t)m * D_INNER + d8]     = *(ushort4*)&o[0];
  *(ushort4*)&xsbf[(size_t)m * D_INNER + d8 + 4] = *(ushort4*)&o[4];
}

// ---------------- x_proj via MFMA: [2048,48] = xs_bf @ xpw_bf^T + b; split dlt/B/C ----------------
__global__ __launch_bounds__(256) void xproj_mfma(
    const __bf16* __restrict__ A, const __bf16* __restrict__ B,
    const float* __restrict__ xpb,
    float* __restrict__ dlt, float* __restrict__ Bm, float* __restrict__ Cm) {
  __shared__ __bf16 As[128][40];
  __shared__ __bf16 Bs[48][40];
  const int tid  = threadIdx.x;
  const int lane = tid & 63;
  const int w    = tid >> 6;                    // wave: rows w*32 .. w*32+31
  const int rowBase = blockIdx.x * 128;

  f32x4 acc[2][3];
  #pragma unroll
  for (int i = 0; i < 2; ++i)
    #pragma unroll
    for (int j = 0; j < 3; ++j) {
      f32x4 z = {0.f, 0.f, 0.f, 0.f};
      acc[i][j] = z;
    }

  const int sr = tid >> 2;          // 0..63
  const int ss = (tid & 3) * 8;     // 0,8,16,24
  const int fr = lane & 15;
  const int fk = (lane >> 4) * 8;

  for (int k0 = 0; k0 < D_INNER; k0 += 32) {
    const __bf16* Ap = A + (size_t)(rowBase + sr) * D_INNER + k0 + ss;
    *(bf16x8*)&As[sr][ss]      = *(const bf16x8*)Ap;
    *(bf16x8*)&As[sr + 64][ss] = *(const bf16x8*)(Ap + (size_t)64 * D_INNER);
    if (tid < 192)
      *(bf16x8*)&Bs[tid >> 2][ss] = *(const bf16x8*)(B + (size_t)(tid >> 2) * D_INNER + k0 + ss);
    __syncthreads();

    bf16x8 af[2], bfr[3];
    #pragma unroll
    for (int mm = 0; mm < 2; ++mm)
      af[mm] = *(const bf16x8*)&As[w * 32 + mm * 16 + fr][fk];
    #pragma unroll
    for (int nn = 0; nn < 3; ++nn)
      bfr[nn] = *(const bf16x8*)&Bs[nn * 16 + fr][fk];
    #pragma unroll
    for (int mm = 0; mm < 2; ++mm)
      #pragma unroll
      for (int nn = 0; nn < 3; ++nn)
        acc[mm][nn] = __builtin_amdgcn_mfma_f32_16x16x32_bf16(af[mm], bfr[nn], acc[mm][nn], 0, 0, 0);
    __syncthreads();
  }

  // C/D layout: col = lane&15, row = (lane>>4)*4 + reg
  const int c16 = lane & 15;
  #pragma unroll
  for (int nn = 0; nn < 3; ++nn) {
    float bv = xpb[nn * 16 + c16];
    float* dst = (nn == 0) ? dlt : (nn == 1) ? Bm : Cm;
    #pragma unroll
    for (int mm = 0; mm < 2; ++mm) {
      int row0 = rowBase + w * 32 + mm * 16 + (lane >> 4) * 4;
      #pragma unroll
      for (int r = 0; r < 4; ++r)
        dst[(size_t)(row0 + r) * 16 + c16] = acc[mm][nn][r] + bv;
    }
  }
}

// ======================= chunked parallel selective scan =======================
// Phase1: per-chunk local scan from h=0 -> Hbuf = local h_end, Sbuf = sum(dv).
// Phase2: sequential combine; Hbuf becomes TRUE h at chunk START (in-place).
// Phase3: replay from true h_start; fuse y, D-skip, gate, bf16 cast.

#define DELTA16(sarr, ttq)                                                       \
  {                                                                              \
    float4 q0 = *(const float4*)&sarr[ttq][0];                                   \
    float4 q1 = *(const float4*)&sarr[ttq][4];                                   \
    float4 q2 = *(const float4*)&sarr[ttq][8];                                   \
    float4 q3 = *(const float4*)&sarr[ttq][12];                                  \
    s += q0.x*dtwr[0] + q0.y*dtwr[1] + q0.z*dtwr[2] + q0.w*dtwr[3];              \
    s += q1.x*dtwr[4] + q1.y*dtwr[5] + q1.z*dtwr[6] + q1.w*dtwr[7];              \
    s += q2.x*dtwr[8] + q2.y*dtwr[9] + q2.z*dtwr[10] + q2.w*dtwr[11];            \
    s += q3.x*dtwr[12] + q3.y*dtwr[13] + q3.z*dtwr[14] + q3.w*dtwr[15];          \
  }

__global__ __launch_bounds__(256) void scan_phase1(
    const unsigned short* __restrict__ xsbf, const float* __restrict__ dlt,
    const float* __restrict__ Bmat, const float* __restrict__ dtw,
    const float* __restrict__ dtb, const float* __restrict__ alog,
    float* __restrict__ Hbuf, float* __restrict__ Sbuf) {
  __shared__ float dltS[CHUNK][16];
  __shared__ float BS[CHUNK][16];
  const int tid = threadIdx.x;
  const int c   = blockIdx.y;
  const int b   = blockIdx.z;
  const int d   = blockIdx.x * 256 + tid;
  const int row0 = b * SEQ + c * CHUNK;
  const __bf16* xsb16 = (const __bf16*)xsbf;
  {
    int e = tid * 2;
    int tt = e >> 4, r = e & 15;
    *(float2*)&dltS[tt][r] = *(const float2*)&dlt[(row0 + tt) * 16 + r];
    *(float2*)&BS[tt][r]   = *(const float2*)&Bmat[(row0 + tt) * 16 + r];
  }
  float dtwr[16], An[16];
  #pragma unroll
  for (int q = 0; q < 4; ++q) {
    float4 w4 = *(const float4*)&dtw[d * 16 + q * 4];
    dtwr[q*4+0] = w4.x; dtwr[q*4+1] = w4.y; dtwr[q*4+2] = w4.z; dtwr[q*4+3] = w4.w;
    float4 a4 = *(const float4*)&alog[d * 16 + q * 4];
    An[q*4+0] = -__expf(a4.x); An[q*4+1] = -__expf(a4.y);
    An[q*4+2] = -__expf(a4.z); An[q*4+3] = -__expf(a4.w);
  }
  const float dtbv = dtb[d];
  float xv[CHUNK];
  #pragma unroll
  for (int tt = 0; tt < CHUNK; ++tt)
    xv[tt] = (float)xsb16[(size_t)(row0 + tt) * D_INNER + d];
  __syncthreads();
  float dv[CHUNK];
  #pragma unroll
  for (int tt = 0; tt < CHUNK; ++tt) {
    float s = dtbv;
    DELTA16(dltS, tt);
    dv[tt] = softplus_f(s);
  }
  float h[16];
  #pragma unroll
  for (int n = 0; n < 16; ++n) h[n] = 0.f;
  float Ssum = 0.f;
  #pragma unroll
  for (int tt = 0; tt < CHUNK; ++tt) {
    const float dvt = dv[tt];
    Ssum += dvt;
    const float dvx = dvt * xv[tt];
    float4 B0 = *(const float4*)&BS[tt][0];
    float4 B1 = *(const float4*)&BS[tt][4];
    float4 B2 = *(const float4*)&BS[tt][8];
    float4 B3 = *(const float4*)&BS[tt][12];
    h[0]  = __expf(dvt*An[0])*h[0]   + dvx*B0.x;
    h[1]  = __expf(dvt*An[1])*h[1]   + dvx*B0.y;
    h[2]  = __expf(dvt*An[2])*h[2]   + dvx*B0.z;
    h[3]  = __expf(dvt*An[3])*h[3]   + dvx*B0.w;
    h[4]  = __expf(dvt*An[4])*h[4]   + dvx*B1.x;
    h[5]  = __expf(dvt*An[5])*h[5]   + dvx*B1.y;
    h[6]  = __expf(dvt*An[6])*h[6]   + dvx*B1.z;
    h[7]  = __expf(dvt*An[7])*h[7]   + dvx*B1.w;
    h[8]  = __expf(dvt*An[8])*h[8]   + dvx*B2.x;
    h[9]  = __expf(dvt*An[9])*h[9]   + dvx*B2.y;
    h[10] = __expf(dvt*An[10])*h[10] + dvx*B2.z;
    h[11] = __expf(dvt*An[11])*h[11] + dvx*B2.w;
    h[12] = __expf(dvt*An[12])*h[12] + dvx*B3.x;
    h[13] = __expf(dvt*An[13])*h[13] + dvx*B3.y;
    h[14] = __expf(dvt*An[14])*h[14] + dvx*B3.z;
    h[15] = __expf(dvt*An[15])*h[15] + dvx*B3.w;
  }
  size_t hbase = (((size_t)(b * NCHUNK + c) * D_INNER) + d) * 16;
  #pragma unroll
  for (int q = 0; q < 4; ++q) {
    float4 o = {h[q*4+0], h[q*4+1], h[q*4+2], h[q*4+3]};
    *(float4*)&Hbuf[hbase + q*4] = o;
  }
  Sbuf[((size_t)b * NCHUNK + c) * D_INNER + d] = Ssum;
}

__global__ __launch_bounds__(256) void scan_phase2(
    const float* __restrict__ alog, const float* __restrict__ Sbuf,
    float* __restrict__ Hbuf) {
  const int tid = threadIdx.x;
  const int n  = tid & 15;
  const int dl = tid >> 4;
  const int d  = blockIdx.x * 16 + dl;
  const int b  = blockIdx.y;
  const float An = -__expf(alog[d * 16 + n]);
  float h_run = 0.f;
  #pragma unroll 4
  for (int c = 0; c < NCHUNK; ++c) {
    size_t idx = (((size_t)(b * NCHUNK + c) * D_INNER) + d) * 16 + n;
    float hend = Hbuf[idx];
    float P = __expf(An * Sbuf[((size_t)b * NCHUNK + c) * D_INNER + d]);
    Hbuf[idx] = h_run;                     // h at chunk START
    h_run = P * h_run + hend;
  }
}

__global__ __launch_bounds__(256) void scan_phase3(
    const unsigned short* __restrict__ xsbf, const unsigned short* __restrict__ xar,
    const float* __restrict__ dlt, const float* __restrict__ Bmat,
    const float* __restrict__ Cmat, const float* __restrict__ dtw,
    const float* __restrict__ dtb, const float* __restrict__ alog,
    const float* __restrict__ Dvec, const float* __restrict__ Hbuf,
    unsigned short* __restrict__ ybf) {
  __shared__ float dltS[CHUNK][16];
  __shared__ float BS[CHUNK][16];
  __shared__ float CS[CHUNK][16];
  const int tid = threadIdx.x;
  const int c   = blockIdx.y;
  const int b   = blockIdx.z;
  const int d   = blockIdx.x * 256 + tid;
  const int row0 = b * SEQ + c * CHUNK;
  const __bf16* xsb16 = (const __bf16*)xsbf;
  const __bf16* xarb  = (const __bf16*)xar;
  {
    int e = tid * 2;
    int tt = e >> 4, r = e & 15;
    *(float2*)&dltS[tt][r] = *(const float2*)&dlt[(row0 + tt) * 16 + r];
    *(float2*)&BS[tt][r]   = *(const float2*)&Bmat[(row0 + tt) * 16 + r];
    *(float2*)&CS[tt][r]   = *(const float2*)&Cmat[(row0 + tt) * 16 + r];
  }
  float dtwr[16], An[16];
  #pragma unroll
  for (int q = 0; q < 4; ++q) {
    float4 w4 = *(const float4*)&dtw[d * 16 + q * 4];
    dtwr[q*4+0] = w4.x; dtwr[q*4+1] = w4.y; dtwr[q*4+2] = w4.z; dtwr[q*4+3] = w4.w;
    float4 a4 = *(const float4*)&alog[d * 16 + q * 4];
    An[q*4+0] = -__expf(a4.x); An[q*4+1] = -__expf(a4.y);
    An[q*4+2] = -__expf(a4.z); An[q*4+3] = -__expf(a4.w);
  }
  const float dtbv = dtb[d];
  const float Dn   = Dvec[d];
  float h[16];
  {
    size_t hbase = (((size_t)(b * NCHUNK + c) * D_INNER) + d) * 16;
    #pragma unroll
    for (int q = 0; q < 4; ++q) {
      float4 hv = *(const float4*)&Hbuf[hbase + q*4];
      h[q*4+0] = hv.x; h[q*4+1] = hv.y; h[q*4+2] = hv.z; h[q*4+3] = hv.w;
    }
  }
  float xv[CHUNK], rv[CHUNK];
  #pragma unroll
  for (int tt = 0; tt < CHUNK; ++tt) {
    xv[tt] = (float)xsb16[(size_t)(row0 + tt) * D_INNER + d];
    rv[tt] = (float)xarb[(size_t)(row0 + tt) * (2 * D_INNER) + D_INNER + d];
  }
  __syncthreads();
  float dv[CHUNK];
  #pragma unroll
  for (int tt = 0; tt < CHUNK; ++tt) {
    float s = dtbv;
    DELTA16(dltS, tt);
    dv[tt] = softplus_f(s);
  }
  #pragma unroll
  for (int tt = 0; tt < CHUNK; ++tt) {
    const float dvt = dv[tt];
    const float dvx = dvt * xv[tt];
    float4 B0 = *(const float4*)&BS[tt][0];
    float4 B1 = *(const float4*)&BS[tt][4];
    float4 B2 = *(const float4*)&BS[tt][8];
    float4 B3 = *(const float4*)&BS[tt][12];
    float4 C0 = *(const float4*)&CS[tt][0];
    float4 C1 = *(const float4*)&CS[tt][4];
    float4 C2 = *(const float4*)&CS[tt][8];
    float4 C3 = *(const float4*)&CS[tt][12];
    float y = 0.f;
    h[0]  = __expf(dvt*An[0])*h[0]   + dvx*B0.x;  y += h[0]*C0.x;
    h[1]  = __expf(dvt*An[1])*h[1]   + dvx*B0.y;  y += h[1]*C0.y;
    h[2]  = __expf(dvt*An[2])*h[2]   + dvx*B0.z;  y += h[2]*C0.z;
    h[3]  = __expf(dvt*An[3])*h[3]   + dvx*B0.w;  y += h[3]*C0.w;
    h[4]  = __expf(dvt*An[4])*h[4]   + dvx*B1.x;  y += h[4]*C1.x;
    h[5]  = __expf(dvt*An[5])*h[5]   + dvx*B1.y;  y += h[5]*C1.y;
    h[6]  = __expf(dvt*An[6])*h[6]   + dvx*B1.z;  y += h[6]*C1.z;
    h[7]  = __expf(dvt*An[7])*h[7]   + dvx*B1.w;  y += h[7]*C1.w;
    h[8]  = __expf(dvt*An[8])*h[8]   + dvx*B2.x;  y += h[8]*C2.x;
    h[9]  = __expf(dvt*An[9])*h[9]   + dvx*B2.y;  y += h[9]*C2.y;
    h[10] = __expf(dvt*An[10])*h[10] + dvx*B2.z;  y += h[10]*C2.z;
    h[11] = __expf(dvt*An[11])*h[11] + dvx*B2.w;  y += h[11]*C2.w;
    h[12] = __expf(dvt*An[12])*h[12] + dvx*B3.x;  y += h[12]*C3.x;
    h[13] = __expf(dvt*An[13])*h[13] + dvx*B3.y;  y += h[13]*C3.y;
    h[14] = __expf(dvt*An[14])*h[14] + dvx*B3.z;  y += h[14]*C3.z;
    h[15] = __expf(dvt*An[15])*h[15] + dvx*B3.w;  y += h[15]*C3.w;
    y += xv[tt] * Dn;
    const float r = rv[tt];
    const float v = y * (r * sigmoid_fast(r));
    ybf[(size_t)(row0 + tt) * D_INNER + d] = f2bf(v);
  }
}

// ---------------- launcher ----------------
extern "C" void kernel_launch(void* const* d_in, const int* in_sizes, int n_in,
                              void* d_out, int out_size, void* d_ws, size_t ws_size,
                              hipStream_t stream) {
  const float* x    = (const float*)d_in[0];
  const float* ipw  = (const float*)d_in[1];
  const float* ipb  = (const float*)d_in[2];
  const float* cw   = (const float*)d_in[3];
  const float* cb   = (const float*)d_in[4];
  const float* xpw  = (const float*)d_in[5];
  const float* xpb  = (const float*)d_in[6];
  const float* dtw  = (const float*)d_in[7];
  const float* dtb  = (const float*)d_in[8];
  const float* alog = (const float*)d_in[9];
  const float* Dv   = (const float*)d_in[10];
  const float* opw  = (const float*)d_in[11];
  const float* opb  = (const float*)d_in[12];
  float* out = (float*)d_out;

  char* ws = (char*)d_ws;
  size_t off = 0;
  auto alloc = [&](size_t bytes) {
    char* p = ws + off;
    off += (bytes + 255) & ~(size_t)255;
    return p;
  };
  unsigned short* xbf   = (unsigned short*)alloc((size_t)M_ROWS * D_MODEL * 2);       // 4 MB
  unsigned short* w1bf  = (unsigned short*)alloc((size_t)2 * D_INNER * D_MODEL * 2);  // 8 MB
  unsigned short* w2bf  = (unsigned short*)alloc((size_t)D_MODEL * D_INNER * 2);      // 4 MB
  unsigned short* xpwbf = (unsigned short*)alloc((size_t)48 * D_INNER * 2);           // 192 KB
  unsigned short* xar   = (unsigned short*)alloc((size_t)M_ROWS * 2 * D_INNER * 2);   // 16 MB (bf16 now)
  unsigned short* xsbf  = (unsigned short*)alloc((size_t)M_ROWS * D_INNER * 2);       // 8 MB (lives conv->p3)
  float* dlt = (float*)alloc((size_t)M_ROWS * 16 * 4);
  float* Bm  = (float*)alloc((size_t)M_ROWS * 16 * 4);
  float* Cm  = (float*)alloc((size_t)M_ROWS * 16 * 4);
  unsigned short* ybf = (unsigned short*)alloc((size_t)M_ROWS * D_INNER * 2);         // 8 MB
  if (off > ws_size) return;
  // w1bf region (8 MB) is dead after gemm1; reused for Hbuf (phase1 -> phase3).
  float* Hbuf = (float*)w1bf;   // [B][NCHUNK][D_INNER][16] f32 = 8 MB exactly
  float* Sbuf = (float*)xbf;    // xbf dead after gemm1; Sbuf = 512 KB

  // 1. casts (x, in_proj_w, out_proj_w, x_proj_w)
  cast_all_kernel<<<8288, 256, 0, stream>>>(x, ipw, opw, xpw, xbf, w1bf, w2bf, xpwbf);
  // 2. in_proj -> bf16 xar (16 MB instead of 32)
  gemm_gll<128, unsigned short><<<dim3(4096 / 128, 2048 / 128), 256, 0, stream>>>(
      (const __bf16*)xbf, (const __bf16*)w1bf, ipb, xar, M_ROWS, 2 * D_INNER, D_MODEL);
  // 3. conv + silu: bf16 in, bf16 out only (8 MB write)
  conv_silu_kernel<<<2048, 256, 0, stream>>>(xar, cw, cb, xsbf);
  // 4. x_proj via MFMA
  xproj_mfma<<<M_ROWS / 128, 256, 0, stream>>>(
      (const __bf16*)xsbf, (const __bf16*)xpwbf, xpb, dlt, Bm, Cm);
  // 5. chunked scan (3 phases), bf16 xs reads
  scan_phase1<<<dim3(D_INNER / 256, NCHUNK, BATCH), 256, 0, stream>>>(
      xsbf, dlt, Bm, dtw, dtb, alog, Hbuf, Sbuf);
  scan_phase2<<<dim3(D_INNER / 16, BATCH), 256, 0, stream>>>(alog, Sbuf, Hbuf);
  scan_phase3<<<dim3(D_INNER / 256, NCHUNK, BATCH), 256, 0, stream>>>(
      xsbf, xar, dlt, Bm, Cm, dtw, dtb, alog, Dv, Hbuf, ybf);
  // 6. out_proj: 64x128 tiles -> 256 wgs, f32 out
  gemm_gll<64, float><<<dim3(1024 / 128, 2048 / 64), 256, 0, stream>>>(
      (const __bf16*)ybf, (const __bf16*)w2bf, opb, out, M_ROWS, D_MODEL, D_INNER);
}

// Round 10
// 249.169 us; speedup vs baseline: 2.0686x; 1.1193x over previous
//
#include <hip/hip_runtime.h>

// ---------------- problem constants ----------------
#define D_MODEL 1024
#define D_STATE 16
#define D_CONV  4
#define D_INNER 2048
#define DT_RANK 16
#define BATCH   2
#define SEQ     1024
#define M_ROWS  (BATCH*SEQ)   // 2048 rows
#define CHUNK   32            // timesteps per scan chunk
#define NCHUNK  (SEQ/CHUNK)   // 32 chunks
#define XP_KSPLIT 16
#define XP_KLEN (D_INNER / XP_KSPLIT)   // 128

typedef __bf16 bf16x8 __attribute__((ext_vector_type(8)));
typedef float  f32x4  __attribute__((ext_vector_type(4)));

__device__ __forceinline__ unsigned short f2bf(float f) {
  unsigned u = __float_as_uint(f);
  u += 0x7fffu + ((u >> 16) & 1u);      // round-to-nearest-even
  return (unsigned short)(u >> 16);
}

__device__ __forceinline__ float sigmoid_fast(float v) {
  return 1.f / (1.f + __expf(-v));
}

__device__ __forceinline__ float softplus_f(float s) {
  return (s > 20.f) ? s : __logf(1.f + __expf(s));
}

// async global->LDS, 16B per lane; LDS dest is wave-uniform base + lane*16 [m97/m104]
__device__ __forceinline__ void gll16(const void* g, void* l) {
  __builtin_amdgcn_global_load_lds(
      (const __attribute__((address_space(1))) unsigned int*)g,
      (__attribute__((address_space(3))) unsigned int*)l, 16, 0, 0);
}

// epilogue store helpers (f32 or bf16 C)
__device__ __forceinline__ void storeC(float v, float* p)          { *p = v; }
__device__ __forceinline__ void storeC(float v, unsigned short* p) { *p = f2bf(v); }

// ---------------- cast f32 -> bf16 (x, in_proj_w, out_proj_w, x_proj_w) + zero dlt/Bm/Cm ----
__global__ __launch_bounds__(256) void cast_all_kernel(
    const float* __restrict__ x, const float* __restrict__ w1, const float* __restrict__ w2,
    const float* __restrict__ xpw,
    unsigned short* __restrict__ xbf, unsigned short* __restrict__ w1bf,
    unsigned short* __restrict__ w2bf, unsigned short* __restrict__ xpwbf,
    float* __restrict__ zbuf /* dlt base; dlt|Bm|Cm contiguous 384 KB */) {
  const int N0 = (M_ROWS * D_MODEL) / 4;        // 524288 float4
  const int N1 = (2 * D_INNER * D_MODEL) / 4;   // 1048576
  const int N2 = (D_MODEL * D_INNER) / 4;       // 524288
  const int N3 = (48 * D_INNER) / 4;            // 24576
  // NZ = 3 * M_ROWS * 16 / 4 = 24576 float4 (zeros for dlt/Bm/Cm)
  int i = blockIdx.x * 256 + threadIdx.x;       // grid = 8384 blocks, covers all exactly
  const float* src; unsigned short* dst; int off;
  if (i < N0)                 { src = x;   dst = xbf;   off = i; }
  else if (i < N0 + N1)       { src = w1;  dst = w1bf;  off = i - N0; }
  else if (i < N0 + N1 + N2)  { src = w2;  dst = w2bf;  off = i - N0 - N1; }
  else if (i < N0 + N1 + N2 + N3) { src = xpw; dst = xpwbf; off = i - N0 - N1 - N2; }
  else {
    float4 z = {0.f, 0.f, 0.f, 0.f};
    ((float4*)zbuf)[i - N0 - N1 - N2 - N3] = z;
    return;
  }
  float4 v = *(const float4*)(src + (size_t)off * 4);
  ushort4 o;
  o.x = f2bf(v.x); o.y = f2bf(v.y); o.z = f2bf(v.z); o.w = f2bf(v.w);
  *(ushort4*)(dst + (size_t)off * 4) = o;
}

// ---------------- bf16 MFMA GEMM with global_load_lds staging (m97 structure) ----------
// NT: C[M,N] = A[M,K] @ B[N,K]^T + bias[N]. CT = float or unsigned short (bf16 out).
template<int BM, typename CT>
__global__ __launch_bounds__(256) void gemm_gll(
    const __bf16* __restrict__ A, const __bf16* __restrict__ B,
    const float* __restrict__ bias, CT* __restrict__ C,
    int M, int N, int K) {
  constexpr int MR = BM / 32;          // M fragments per wave (2 or 4)
  __shared__ __bf16 As[BM][32];
  __shared__ __bf16 Bs[128][32];
  const int tid  = threadIdx.x;
  const int lane = tid & 63;
  const int w    = tid >> 6;
  const int wr   = w >> 1, wc = w & 1;
  const int rowBase = blockIdx.y * BM;
  const int colBase = blockIdx.x * 128;

  f32x4 acc[MR][4];
  #pragma unroll
  for (int i = 0; i < MR; ++i)
    #pragma unroll
    for (int j = 0; j < 4; ++j) { f32x4 z = {0.f,0.f,0.f,0.f}; acc[i][j] = z; }

  const int srow = lane >> 2;        // staging row within 16-row group
  const int sk   = (lane & 3) * 8;   // staging k element offset
  const int fr   = lane & 15;
  const int fk   = (lane >> 4) * 8;

  for (int k0 = 0; k0 < K; k0 += 32) {
    #pragma unroll
    for (int i = 0; i < BM / 64; ++i) {
      const int r0 = w * (BM / 4) + i * 16;
      gll16(A + (size_t)(rowBase + r0 + srow) * K + k0 + sk, &As[r0][0]);
    }
    #pragma unroll
    for (int i = 0; i < 2; ++i) {
      const int r0 = w * 32 + i * 16;
      gll16(B + (size_t)(colBase + r0 + srow) * K + k0 + sk, &Bs[r0][0]);
    }
    __syncthreads();

    bf16x8 af[MR], bfr[4];
    #pragma unroll
    for (int mm = 0; mm < MR; ++mm)
      af[mm] = *(const bf16x8*)&As[wr * (BM / 2) + mm * 16 + fr][fk];
    #pragma unroll
    for (int nn = 0; nn < 4; ++nn)
      bfr[nn] = *(const bf16x8*)&Bs[wc * 64 + nn * 16 + fr][fk];
    #pragma unroll
    for (int mm = 0; mm < MR; ++mm)
      #pragma unroll
      for (int nn = 0; nn < 4; ++nn)
        acc[mm][nn] = __builtin_amdgcn_mfma_f32_16x16x32_bf16(af[mm], bfr[nn], acc[mm][nn], 0, 0, 0);
    __syncthreads();
  }

  // epilogue: C/D layout col=lane&15, row=(lane>>4)*4+reg  [verified m89/m91]
  #pragma unroll
  for (int nn = 0; nn < 4; ++nn) {
    int col = colBase + wc * 64 + nn * 16 + fr;
    float bv = bias[col];
    #pragma unroll
    for (int mm = 0; mm < MR; ++mm) {
      int row0 = rowBase + wr * (BM / 2) + mm * 16 + (lane >> 4) * 4;
      #pragma unroll
      for (int r = 0; r < 4; ++r)
        storeC(acc[mm][nn][r] + bv, &C[(size_t)(row0 + r) * N + col]);
    }
  }
}

// ---------------- causal depthwise conv (k=4) + bias + SiLU ----------------
// reads bf16 xar (xs branch, cols 0..2047), writes bf16 xs ONLY (8 MB).
__global__ __launch_bounds__(256) void conv_silu_kernel(
    const unsigned short* __restrict__ xar, const float* __restrict__ cw,
    const float* __restrict__ cb, unsigned short* __restrict__ xsbf) {
  int idx = blockIdx.x * 256 + threadIdx.x;     // one bf16x8 of d per thread
  int m  = idx >> 8;                            // row (b*1024 + t)
  int d8 = (idx & 255) << 3;                    // d offset (0..2040)
  int t  = m & (SEQ - 1);
  const __bf16* xarb = (const __bf16*)xar;

  float4 cwl[8];
  const float4* cw4 = (const float4*)cw;        // cw[d][0..3] contiguous
  #pragma unroll
  for (int e = 0; e < 8; ++e) cwl[e] = cw4[d8 + e];

  float acc[8];
  #pragma unroll
  for (int e = 0; e < 8; ++e) acc[e] = cb[d8 + e];

  #pragma unroll
  for (int j = 0; j < 4; ++j) {
    int tt = t - 3 + j;
    if (tt < 0) continue;                       // causal left zero-pad (per batch)
    bf16x8 v = *(const bf16x8*)&xarb[(size_t)(m - 3 + j) * (2 * D_INNER) + d8];
    const float* cj = (const float*)cwl;
    #pragma unroll
    for (int e = 0; e < 8; ++e)
      acc[e] += (float)v[e] * cj[e * 4 + j];
  }
  unsigned short o[8];
  #pragma unroll
  for (int e = 0; e < 8; ++e) {
    float s = acc[e] * sigmoid_fast(acc[e]);
    o[e] = f2bf(s);
  }
  *(ushort4*)&xsbf[(size_t)m * D_INNER + d8]     = *(ushort4*)&o[0];
  *(ushort4*)&xsbf[(size_t)m * D_INNER + d8 + 4] = *(ushort4*)&o[4];
}

// ---------------- x_proj via MFMA, K-SPLIT: [2048,48] = xs_bf @ xpw_bf^T + b ----------
// grid (32 row-tiles, 16 k-splits) = 512 blocks. 64-row tile, wave w owns rows
// w*16..w*16+15 (1x3 fragments). Each block reduces K=128 (4 BK=32 iters) and
// atomicAdds partials into dlt/Bm/Cm (zero-initialized by cast_all).
__global__ __launch_bounds__(256) void xproj_mfma(
    const __bf16* __restrict__ A, const __bf16* __restrict__ B,
    const float* __restrict__ xpb,
    float* __restrict__ dlt, float* __restrict__ Bm, float* __restrict__ Cm) {
  __shared__ __bf16 As[64][32];
  __shared__ __bf16 Bs[48][32];
  const int tid  = threadIdx.x;
  const int lane = tid & 63;
  const int w    = tid >> 6;
  const int rowBase = blockIdx.x * 64;
  const int kbase   = blockIdx.y * XP_KLEN;

  f32x4 acc[3];
  #pragma unroll
  for (int j = 0; j < 3; ++j) { f32x4 z = {0.f,0.f,0.f,0.f}; acc[j] = z; }

  const int srow = lane >> 2;
  const int sk   = (lane & 3) * 8;
  const int fr   = lane & 15;
  const int fk   = (lane >> 4) * 8;

  for (int k0 = kbase; k0 < kbase + XP_KLEN; k0 += 32) {
    gll16(A + (size_t)(rowBase + w * 16 + srow) * D_INNER + k0 + sk, &As[w * 16][0]);
    if (w < 3)
      gll16(B + (size_t)(w * 16 + srow) * D_INNER + k0 + sk, &Bs[w * 16][0]);
    __syncthreads();
    bf16x8 af = *(const bf16x8*)&As[w * 16 + fr][fk];
    #pragma unroll
    for (int nn = 0; nn < 3; ++nn) {
      bf16x8 bv = *(const bf16x8*)&Bs[nn * 16 + fr][fk];
      acc[nn] = __builtin_amdgcn_mfma_f32_16x16x32_bf16(af, bv, acc[nn], 0, 0, 0);
    }
    __syncthreads();
  }

  // C/D layout: col = lane&15, row = (lane>>4)*4 + reg. Bias only from ksplit 0.
  const int c16 = lane & 15;
  const float biasOn = (blockIdx.y == 0) ? 1.f : 0.f;
  #pragma unroll
  for (int nn = 0; nn < 3; ++nn) {
    float bv = biasOn * xpb[nn * 16 + c16];
    float* dst = (nn == 0) ? dlt : (nn == 1) ? Bm : Cm;
    int row0 = rowBase + w * 16 + (lane >> 4) * 4;
    #pragma unroll
    for (int r = 0; r < 4; ++r)
      atomicAdd(&dst[(size_t)(row0 + r) * 16 + c16], acc[nn][r] + bv);
  }
}

// ======================= chunked parallel selective scan =======================
// Phase1: per-chunk local scan from h=0 -> Hbuf = local h_end, Sbuf = sum(dv).
// Phase2: sequential combine; Hbuf becomes TRUE h at chunk START (in-place).
// Phase3: replay from true h_start; fuse y, D-skip, gate, bf16 cast.

#define DELTA16(sarr, ttq)                                                       \
  {                                                                              \
    float4 q0 = *(const float4*)&sarr[ttq][0];                                   \
    float4 q1 = *(const float4*)&sarr[ttq][4];                                   \
    float4 q2 = *(const float4*)&sarr[ttq][8];                                   \
    float4 q3 = *(const float4*)&sarr[ttq][12];                                  \
    s += q0.x*dtwr[0] + q0.y*dtwr[1] + q0.z*dtwr[2] + q0.w*dtwr[3];              \
    s += q1.x*dtwr[4] + q1.y*dtwr[5] + q1.z*dtwr[6] + q1.w*dtwr[7];              \
    s += q2.x*dtwr[8] + q2.y*dtwr[9] + q2.z*dtwr[10] + q2.w*dtwr[11];            \
    s += q3.x*dtwr[12] + q3.y*dtwr[13] + q3.z*dtwr[14] + q3.w*dtwr[15];          \
  }

__global__ __launch_bounds__(256) void scan_phase1(
    const unsigned short* __restrict__ xsbf, const float* __restrict__ dlt,
    const float* __restrict__ Bmat, const float* __restrict__ dtw,
    const float* __restrict__ dtb, const float* __restrict__ alog,
    float* __restrict__ Hbuf, float* __restrict__ Sbuf) {
  __shared__ float dltS[CHUNK][16];
  __shared__ float BS[CHUNK][16];
  const int tid = threadIdx.x;
  const int c   = blockIdx.y;
  const int b   = blockIdx.z;
  const int d   = blockIdx.x * 256 + tid;
  const int row0 = b * SEQ + c * CHUNK;
  const __bf16* xsb16 = (const __bf16*)xsbf;
  {
    int e = tid * 2;
    int tt = e >> 4, r = e & 15;
    *(float2*)&dltS[tt][r] = *(const float2*)&dlt[(row0 + tt) * 16 + r];
    *(float2*)&BS[tt][r]   = *(const float2*)&Bmat[(row0 + tt) * 16 + r];
  }
  float dtwr[16], An[16];
  #pragma unroll
  for (int q = 0; q < 4; ++q) {
    float4 w4 = *(const float4*)&dtw[d * 16 + q * 4];
    dtwr[q*4+0] = w4.x; dtwr[q*4+1] = w4.y; dtwr[q*4+2] = w4.z; dtwr[q*4+3] = w4.w;
    float4 a4 = *(const float4*)&alog[d * 16 + q * 4];
    An[q*4+0] = -__expf(a4.x); An[q*4+1] = -__expf(a4.y);
    An[q*4+2] = -__expf(a4.z); An[q*4+3] = -__expf(a4.w);
  }
  const float dtbv = dtb[d];
  float xv[CHUNK];
  #pragma unroll
  for (int tt = 0; tt < CHUNK; ++tt)
    xv[tt] = (float)xsb16[(size_t)(row0 + tt) * D_INNER + d];
  __syncthreads();
  float dv[CHUNK];
  #pragma unroll
  for (int tt = 0; tt < CHUNK; ++tt) {
    float s = dtbv;
    DELTA16(dltS, tt);
    dv[tt] = softplus_f(s);
  }
  float h[16];
  #pragma unroll
  for (int n = 0; n < 16; ++n) h[n] = 0.f;
  float Ssum = 0.f;
  #pragma unroll
  for (int tt = 0; tt < CHUNK; ++tt) {
    const float dvt = dv[tt];
    Ssum += dvt;
    const float dvx = dvt * xv[tt];
    float4 B0 = *(const float4*)&BS[tt][0];
    float4 B1 = *(const float4*)&BS[tt][4];
    float4 B2 = *(const float4*)&BS[tt][8];
    float4 B3 = *(const float4*)&BS[tt][12];
    h[0]  = __expf(dvt*An[0])*h[0]   + dvx*B0.x;
    h[1]  = __expf(dvt*An[1])*h[1]   + dvx*B0.y;
    h[2]  = __expf(dvt*An[2])*h[2]   + dvx*B0.z;
    h[3]  = __expf(dvt*An[3])*h[3]   + dvx*B0.w;
    h[4]  = __expf(dvt*An[4])*h[4]   + dvx*B1.x;
    h[5]  = __expf(dvt*An[5])*h[5]   + dvx*B1.y;
    h[6]  = __expf(dvt*An[6])*h[6]   + dvx*B1.z;
    h[7]  = __expf(dvt*An[7])*h[7]   + dvx*B1.w;
    h[8]  = __expf(dvt*An[8])*h[8]   + dvx*B2.x;
    h[9]  = __expf(dvt*An[9])*h[9]   + dvx*B2.y;
    h[10] = __expf(dvt*An[10])*h[10] + dvx*B2.z;
    h[11] = __expf(dvt*An[11])*h[11] + dvx*B2.w;
    h[12] = __expf(dvt*An[12])*h[12] + dvx*B3.x;
    h[13] = __expf(dvt*An[13])*h[13] + dvx*B3.y;
    h[14] = __expf(dvt*An[14])*h[14] + dvx*B3.z;
    h[15] = __expf(dvt*An[15])*h[15] + dvx*B3.w;
  }
  size_t hbase = (((size_t)(b * NCHUNK + c) * D_INNER) + d) * 16;
  #pragma unroll
  for (int q = 0; q < 4; ++q) {
    float4 o = {h[q*4+0], h[q*4+1], h[q*4+2], h[q*4+3]};
    *(float4*)&Hbuf[hbase + q*4] = o;
  }
  Sbuf[((size_t)b * NCHUNK + c) * D_INNER + d] = Ssum;
}

__global__ __launch_bounds__(256) void scan_phase2(
    const float* __restrict__ alog, const float* __restrict__ Sbuf,
    float* __restrict__ Hbuf) {
  const int tid = threadIdx.x;
  const int n  = tid & 15;
  const int dl = tid >> 4;
  const int d  = blockIdx.x * 16 + dl;
  const int b  = blockIdx.y;
  const float An = -__expf(alog[d * 16 + n]);
  float h_run = 0.f;
  #pragma unroll 4
  for (int c = 0; c < NCHUNK; ++c) {
    size_t idx = (((size_t)(b * NCHUNK + c) * D_INNER) + d) * 16 + n;
    float hend = Hbuf[idx];
    float P = __expf(An * Sbuf[((size_t)b * NCHUNK + c) * D_INNER + d]);
    Hbuf[idx] = h_run;                     // h at chunk START
    h_run = P * h_run + hend;
  }
}

__global__ __launch_bounds__(256) void scan_phase3(
    const unsigned short* __restrict__ xsbf, const unsigned short* __restrict__ xar,
    const float* __restrict__ dlt, const float* __restrict__ Bmat,
    const float* __restrict__ Cmat, const float* __restrict__ dtw,
    const float* __restrict__ dtb, const float* __restrict__ alog,
    const float* __restrict__ Dvec, const float* __restrict__ Hbuf,
    unsigned short* __restrict__ ybf) {
  __shared__ float dltS[CHUNK][16];
  __shared__ float BS[CHUNK][16];
  __shared__ float CS[CHUNK][16];
  const int tid = threadIdx.x;
  const int c   = blockIdx.y;
  const int b   = blockIdx.z;
  const int d   = blockIdx.x * 256 + tid;
  const int row0 = b * SEQ + c * CHUNK;
  const __bf16* xsb16 = (const __bf16*)xsbf;
  const __bf16* xarb  = (const __bf16*)xar;
  {
    int e = tid * 2;
    int tt = e >> 4, r = e & 15;
    *(float2*)&dltS[tt][r] = *(const float2*)&dlt[(row0 + tt) * 16 + r];
    *(float2*)&BS[tt][r]   = *(const float2*)&Bmat[(row0 + tt) * 16 + r];
    *(float2*)&CS[tt][r]   = *(const float2*)&Cmat[(row0 + tt) * 16 + r];
  }
  float dtwr[16], An[16];
  #pragma unroll
  for (int q = 0; q < 4; ++q) {
    float4 w4 = *(const float4*)&dtw[d * 16 + q * 4];
    dtwr[q*4+0] = w4.x; dtwr[q*4+1] = w4.y; dtwr[q*4+2] = w4.z; dtwr[q*4+3] = w4.w;
    float4 a4 = *(const float4*)&alog[d * 16 + q * 4];
    An[q*4+0] = -__expf(a4.x); An[q*4+1] = -__expf(a4.y);
    An[q*4+2] = -__expf(a4.z); An[q*4+3] = -__expf(a4.w);
  }
  const float dtbv = dtb[d];
  const float Dn   = Dvec[d];
  float h[16];
  {
    size_t hbase = (((size_t)(b * NCHUNK + c) * D_INNER) + d) * 16;
    #pragma unroll
    for (int q = 0; q < 4; ++q) {
      float4 hv = *(const float4*)&Hbuf[hbase + q*4];
      h[q*4+0] = hv.x; h[q*4+1] = hv.y; h[q*4+2] = hv.z; h[q*4+3] = hv.w;
    }
  }
  float xv[CHUNK], rv[CHUNK];
  #pragma unroll
  for (int tt = 0; tt < CHUNK; ++tt) {
    xv[tt] = (float)xsb16[(size_t)(row0 + tt) * D_INNER + d];
    rv[tt] = (float)xarb[(size_t)(row0 + tt) * (2 * D_INNER) + D_INNER + d];
  }
  __syncthreads();
  float dv[CHUNK];
  #pragma unroll
  for (int tt = 0; tt < CHUNK; ++tt) {
    float s = dtbv;
    DELTA16(dltS, tt);
    dv[tt] = softplus_f(s);
  }
  #pragma unroll
  for (int tt = 0; tt < CHUNK; ++tt) {
    const float dvt = dv[tt];
    const float dvx = dvt * xv[tt];
    float4 B0 = *(const float4*)&BS[tt][0];
    float4 B1 = *(const float4*)&BS[tt][4];
    float4 B2 = *(const float4*)&BS[tt][8];
    float4 B3 = *(const float4*)&BS[tt][12];
    float4 C0 = *(const float4*)&CS[tt][0];
    float4 C1 = *(const float4*)&CS[tt][4];
    float4 C2 = *(const float4*)&CS[tt][8];
    float4 C3 = *(const float4*)&CS[tt][12];
    float y = 0.f;
    h[0]  = __expf(dvt*An[0])*h[0]   + dvx*B0.x;  y += h[0]*C0.x;
    h[1]  = __expf(dvt*An[1])*h[1]   + dvx*B0.y;  y += h[1]*C0.y;
    h[2]  = __expf(dvt*An[2])*h[2]   + dvx*B0.z;  y += h[2]*C0.z;
    h[3]  = __expf(dvt*An[3])*h[3]   + dvx*B0.w;  y += h[3]*C0.w;
    h[4]  = __expf(dvt*An[4])*h[4]   + dvx*B1.x;  y += h[4]*C1.x;
    h[5]  = __expf(dvt*An[5])*h[5]   + dvx*B1.y;  y += h[5]*C1.y;
    h[6]  = __expf(dvt*An[6])*h[6]   + dvx*B1.z;  y += h[6]*C1.z;
    h[7]  = __expf(dvt*An[7])*h[7]   + dvx*B1.w;  y += h[7]*C1.w;
    h[8]  = __expf(dvt*An[8])*h[8]   + dvx*B2.x;  y += h[8]*C2.x;
    h[9]  = __expf(dvt*An[9])*h[9]   + dvx*B2.y;  y += h[9]*C2.y;
    h[10] = __expf(dvt*An[10])*h[10] + dvx*B2.z;  y += h[10]*C2.z;
    h[11] = __expf(dvt*An[11])*h[11] + dvx*B2.w;  y += h[11]*C2.w;
    h[12] = __expf(dvt*An[12])*h[12] + dvx*B3.x;  y += h[12]*C3.x;
    h[13] = __expf(dvt*An[13])*h[13] + dvx*B3.y;  y += h[13]*C3.y;
    h[14] = __expf(dvt*An[14])*h[14] + dvx*B3.z;  y += h[14]*C3.z;
    h[15] = __expf(dvt*An[15])*h[15] + dvx*B3.w;  y += h[15]*C3.w;
    y += xv[tt] * Dn;
    const float r = rv[tt];
    const float v = y * (r * sigmoid_fast(r));
    ybf[(size_t)(row0 + tt) * D_INNER + d] = f2bf(v);
  }
}

// ---------------- launcher ----------------
extern "C" void kernel_launch(void* const* d_in, const int* in_sizes, int n_in,
                              void* d_out, int out_size, void* d_ws, size_t ws_size,
                              hipStream_t stream) {
  const float* x    = (const float*)d_in[0];
  const float* ipw  = (const float*)d_in[1];
  const float* ipb  = (const float*)d_in[2];
  const float* cw   = (const float*)d_in[3];
  const float* cb   = (const float*)d_in[4];
  const float* xpw  = (const float*)d_in[5];
  const float* xpb  = (const float*)d_in[6];
  const float* dtw  = (const float*)d_in[7];
  const float* dtb  = (const float*)d_in[8];
  const float* alog = (const float*)d_in[9];
  const float* Dv   = (const float*)d_in[10];
  const float* opw  = (const float*)d_in[11];
  const float* opb  = (const float*)d_in[12];
  float* out = (float*)d_out;

  char* ws = (char*)d_ws;
  size_t off = 0;
  auto alloc = [&](size_t bytes) {
    char* p = ws + off;
    off += (bytes + 255) & ~(size_t)255;
    return p;
  };
  unsigned short* xbf   = (unsigned short*)alloc((size_t)M_ROWS * D_MODEL * 2);       // 4 MB
  unsigned short* w1bf  = (unsigned short*)alloc((size_t)2 * D_INNER * D_MODEL * 2);  // 8 MB
  unsigned short* w2bf  = (unsigned short*)alloc((size_t)D_MODEL * D_INNER * 2);      // 4 MB
  unsigned short* xpwbf = (unsigned short*)alloc((size_t)48 * D_INNER * 2);           // 192 KB
  unsigned short* xar   = (unsigned short*)alloc((size_t)M_ROWS * 2 * D_INNER * 2);   // 16 MB bf16
  unsigned short* xsbf  = (unsigned short*)alloc((size_t)M_ROWS * D_INNER * 2);       // 8 MB
  float* dlt = (float*)alloc((size_t)M_ROWS * 16 * 4);   // 128 KB  } contiguous
  float* Bm  = (float*)alloc((size_t)M_ROWS * 16 * 4);   // 128 KB  } 384 KB zeroed
  float* Cm  = (float*)alloc((size_t)M_ROWS * 16 * 4);   // 128 KB  } by cast_all
  unsigned short* ybf = (unsigned short*)alloc((size_t)M_ROWS * D_INNER * 2);         // 8 MB
  if (off > ws_size) return;
  // w1bf region (8 MB) is dead after gemm1; reused for Hbuf (phase1 -> phase3).
  float* Hbuf = (float*)w1bf;   // [B][NCHUNK][D_INNER][16] f32 = 8 MB exactly
  float* Sbuf = (float*)xbf;    // xbf dead after gemm1; Sbuf = 512 KB

  // 1. casts + zero dlt/Bm/Cm. Grid: (524288+1048576+524288+24576+24576)/256 = 8384
  cast_all_kernel<<<8384, 256, 0, stream>>>(x, ipw, opw, xpw, xbf, w1bf, w2bf, xpwbf, dlt);
  // 2. in_proj -> bf16 xar
  gemm_gll<128, unsigned short><<<dim3(4096 / 128, 2048 / 128), 256, 0, stream>>>(
      (const __bf16*)xbf, (const __bf16*)w1bf, ipb, xar, M_ROWS, 2 * D_INNER, D_MODEL);
  // 3. conv + silu: bf16 in, bf16 out
  conv_silu_kernel<<<2048, 256, 0, stream>>>(xar, cw, cb, xsbf);
  // 4. x_proj via K-split MFMA + atomics: grid (32, 16) = 512 blocks
  xproj_mfma<<<dim3(M_ROWS / 64, XP_KSPLIT), 256, 0, stream>>>(
      (const __bf16*)xsbf, (const __bf16*)xpwbf, xpb, dlt, Bm, Cm);
  // 5. chunked scan (3 phases)
  scan_phase1<<<dim3(D_INNER / 256, NCHUNK, BATCH), 256, 0, stream>>>(
      xsbf, dlt, Bm, dtw, dtb, alog, Hbuf, Sbuf);
  scan_phase2<<<dim3(D_INNER / 16, BATCH), 256, 0, stream>>>(alog, Sbuf, Hbuf);
  scan_phase3<<<dim3(D_INNER / 256, NCHUNK, BATCH), 256, 0, stream>>>(
      xsbf, xar, dlt, Bm, Cm, dtw, dtb, alog, Dv, Hbuf, ybf);
  // 6. out_proj: 64x128 tiles -> 256 wgs, f32 out
  gemm_gll<64, float><<<dim3(1024 / 128, 2048 / 64), 256, 0, stream>>>(
      (const __bf16*)ybf, (const __bf16*)w2bf, opb, out, M_ROWS, D_MODEL, D_INNER);
}